// Round 10
// baseline (1143.430 us; speedup 1.0000x reference)
//
#include <hip/hip_runtime.h>
#include <math.h>

// ---------------------------------------------------------------------------
// Graph U-Net forward on MI355X.
// Down path = bf16x6 split MFMA (~3e-8 rel err) with reg-prefetch pipelines.
// Non-ordering layers = multi-head bf16 MFMA GAT. Transposes fused into GEMM
// epilogues; unpool via inverse-rank; all stage loads prefetched.
// ---------------------------------------------------------------------------

typedef short bf16x8 __attribute__((ext_vector_type(8)));
typedef float f32x4 __attribute__((ext_vector_type(4)));

static __device__ __forceinline__ float wave_sum64(float v) {
#pragma unroll
  for (int off = 32; off; off >>= 1) v += __shfl_down(v, off);
  return v;
}

static __device__ __forceinline__ unsigned short f2b(float x) {
  unsigned u = __float_as_uint(x);
  unsigned r = (u + 0x7fffu + ((u >> 16) & 1u)) >> 16;
  return (unsigned short)r;
}

static __device__ __forceinline__ float b2f(unsigned short h) {
  return __uint_as_float(((unsigned)h) << 16);
}

// A0 = A + I  (4096x4096), float4
__global__ void k_add_eye(const float* __restrict__ A, float* __restrict__ O) {
  size_t i = ((size_t)blockIdx.x * 256 + threadIdx.x) * 4;
  size_t r = i >> 12, c = i & 4095;
  float4 v = *reinterpret_cast<const float4*>(&A[i]);
  if (r >= c && r < c + 4) ((float*)&v)[r - c] += 1.f;
  *reinterpret_cast<float4*>(&O[i]) = v;
}

// row-major 3-plane bf16 split: D[p*PS + i] = split_p(S[i])
__global__ void k_split3(const float* __restrict__ S, unsigned short* __restrict__ D,
                         size_t PS, int n) {
  int stride = gridDim.x * 1024;
  for (int i = (blockIdx.x * 256 + threadIdx.x) * 4; i < n; i += stride) {
    float4 v = *reinterpret_cast<const float4*>(&S[i]);
    float xv[4] = {v.x, v.y, v.z, v.w};
    unsigned short o1[4], o2[4], o3[4];
#pragma unroll
    for (int e = 0; e < 4; ++e) {
      float x = xv[e];
      unsigned short a = f2b(x);
      float r1 = x - b2f(a);
      unsigned short b = f2b(r1);
      float r2 = r1 - b2f(b);
      o1[e] = a; o2[e] = b; o3[e] = f2b(r2);
    }
    *reinterpret_cast<uint2*>(&D[i]) = *reinterpret_cast<const uint2*>(o1);
    *reinterpret_cast<uint2*>(&D[PS + i]) = *reinterpret_cast<const uint2*>(o2);
    *reinterpret_cast<uint2*>(&D[2 * PS + i]) = *reinterpret_cast<const uint2*>(o3);
  }
}

// gather rows + scale + 3-plane split
__global__ void k_gather_scale_split3(const float* __restrict__ Xs, int Dd,
    const int* __restrict__ idx, const float* __restrict__ v,
    unsigned short* __restrict__ D, size_t PS) {
  int i = blockIdx.y;
  int f = (blockIdx.x * 256 + threadIdx.x) * 4;
  if (f >= Dd) return;
  float vi = v[i];
  float4 x4 = *reinterpret_cast<const float4*>(&Xs[(size_t)idx[i] * Dd + f]);
  float xv[4] = {x4.x * vi, x4.y * vi, x4.z * vi, x4.w * vi};
  unsigned short o1[4], o2[4], o3[4];
#pragma unroll
  for (int e = 0; e < 4; ++e) {
    float x = xv[e];
    unsigned short a = f2b(x);
    float r1 = x - b2f(a);
    unsigned short b = f2b(r1);
    float r2 = r1 - b2f(b);
    o1[e] = a; o2[e] = b; o3[e] = f2b(r2);
  }
  size_t e0 = (size_t)i * Dd + f;
  *reinterpret_cast<uint2*>(&D[e0]) = *reinterpret_cast<const uint2*>(o1);
  *reinterpret_cast<uint2*>(&D[PS + e0]) = *reinterpret_cast<const uint2*>(o2);
  *reinterpret_cast<uint2*>(&D[2 * PS + e0]) = *reinterpret_cast<const uint2*>(o3);
}

// gather rows + scale -> bf16
__global__ void k_gather_scale_b16(const float* __restrict__ Xs, int Dd,
    const int* __restrict__ idx, const float* __restrict__ v,
    unsigned short* __restrict__ D) {
  int i = blockIdx.y;
  int f = (blockIdx.x * 256 + threadIdx.x) * 4;
  if (f >= Dd) return;
  float vi = v[i];
  float4 x4 = *reinterpret_cast<const float4*>(&Xs[(size_t)idx[i] * Dd + f]);
  unsigned short o[4] = {f2b(x4.x * vi), f2b(x4.y * vi), f2b(x4.z * vi), f2b(x4.w * vi)};
  *reinterpret_cast<uint2*>(&D[(size_t)i * Dd + f]) = *reinterpret_cast<const uint2*>(o);
}

// D[c][r] = bf16(S[r*ldS + c]); f32 in
__global__ __launch_bounds__(256) void k_transpose_bf16(const float* __restrict__ S, int ldS,
    unsigned short* __restrict__ D, int R, int Cc) {
  __shared__ unsigned short T[64][72];
  int r0 = blockIdx.y << 6, c0 = blockIdx.x << 6;
  int tid = threadIdx.x;
  int tr = tid >> 4, tc4 = (tid & 15) << 2;
#pragma unroll
  for (int q = 0; q < 4; ++q) {
    int row = tr + q * 16;
    float4 v = *reinterpret_cast<const float4*>(&S[(size_t)(r0 + row) * ldS + c0 + tc4]);
    T[tc4 + 0][row] = f2b(v.x);
    T[tc4 + 1][row] = f2b(v.y);
    T[tc4 + 2][row] = f2b(v.z);
    T[tc4 + 3][row] = f2b(v.w);
  }
  __syncthreads();
#pragma unroll
  for (int q = 0; q < 4; ++q) {
    int row = tr + q * 16;
    *reinterpret_cast<uint2*>(&D[(size_t)(c0 + row) * R + r0 + tc4]) =
        *reinterpret_cast<const uint2*>(&T[row][tc4]);
  }
}

// D[c][r] = S[r*ldS + c]; bf16 in/out
__global__ __launch_bounds__(256) void k_transpose_bb(const unsigned short* __restrict__ S,
    int ldS, unsigned short* __restrict__ D, int R, int Cc) {
  __shared__ unsigned short T[64][72];
  int r0 = blockIdx.y << 6, c0 = blockIdx.x << 6;
  int tid = threadIdx.x;
  int tr = tid >> 4, tc4 = (tid & 15) << 2;
#pragma unroll
  for (int q = 0; q < 4; ++q) {
    int row = tr + q * 16;
    uint2 v = *reinterpret_cast<const uint2*>(&S[(size_t)(r0 + row) * ldS + c0 + tc4]);
    const unsigned short* p = (const unsigned short*)&v;
    T[tc4 + 0][row] = p[0]; T[tc4 + 1][row] = p[1];
    T[tc4 + 2][row] = p[2]; T[tc4 + 3][row] = p[3];
  }
  __syncthreads();
#pragma unroll
  for (int q = 0; q < 4; ++q) {
    int row = tr + q * 16;
    *reinterpret_cast<uint2*>(&D[(size_t)(c0 + row) * R + r0 + tc4]) =
        *reinterpret_cast<const uint2*>(&T[row][tc4]);
  }
}

// per-head transpose: D[(h*F + c)*R + r] = bf16(S[r*ldS + h*F + c])
__global__ __launch_bounds__(256) void k_transpose_bf16h(const float* __restrict__ S, int ldS,
    int F, unsigned short* __restrict__ D, int R) {
  __shared__ unsigned short T[64][72];
  int h = blockIdx.z;
  int r0 = blockIdx.y << 6, c0 = blockIdx.x << 6;
  int tid = threadIdx.x;
  int tr = tid >> 4, tc4 = (tid & 15) << 2;
#pragma unroll
  for (int q = 0; q < 4; ++q) {
    int row = tr + q * 16;
    float4 v = *reinterpret_cast<const float4*>(&S[(size_t)(r0 + row) * ldS + h * F + c0 + tc4]);
    T[tc4 + 0][row] = f2b(v.x);
    T[tc4 + 1][row] = f2b(v.y);
    T[tc4 + 2][row] = f2b(v.z);
    T[tc4 + 3][row] = f2b(v.w);
  }
  __syncthreads();
#pragma unroll
  for (int q = 0; q < 4; ++q) {
    int row = tr + q * 16;
    *reinterpret_cast<uint2*>(&D[((size_t)h * F + c0 + row) * R + r0 + tc4]) =
        *reinterpret_cast<const uint2*>(&T[row][tc4]);
  }
}

// 3-way split + transpose (weights only now)
__global__ __launch_bounds__(256) void k_transpose_split(const float* __restrict__ S, int ldS,
    int F, unsigned short* __restrict__ D, int R, size_t PS) {
  __shared__ unsigned short T[3][64][72];
  int h = blockIdx.z;
  int c0 = blockIdx.x << 6, r0 = blockIdx.y << 6;
  int tid = threadIdx.x;
  int tr = tid >> 4, tc4 = (tid & 15) << 2;
#pragma unroll
  for (int q = 0; q < 4; ++q) {
    int row = tr + q * 16;
    float4 v = *reinterpret_cast<const float4*>(&S[(size_t)(r0 + row) * ldS + h * F + c0 + tc4]);
    float xv[4] = {v.x, v.y, v.z, v.w};
#pragma unroll
    for (int e = 0; e < 4; ++e) {
      float x = xv[e];
      unsigned short h1 = f2b(x);
      float r1 = x - b2f(h1);
      unsigned short h2 = f2b(r1);
      float r2 = r1 - b2f(h2);
      T[0][tc4 + e][row] = h1;
      T[1][tc4 + e][row] = h2;
      T[2][tc4 + e][row] = f2b(r2);
    }
  }
  __syncthreads();
#pragma unroll
  for (int p = 0; p < 3; ++p)
#pragma unroll
    for (int q = 0; q < 4; ++q) {
      int row = tr + q * 16;
      *reinterpret_cast<uint2*>(&D[p * PS + (size_t)(h * F + c0 + row) * R + r0 + tc4]) =
          *reinterpret_cast<const uint2*>(&T[p][row][tc4]);
    }
}

// ---- bf16x6 GEMM with reg-prefetch; epilogue writes C f32 + optional 3-plane
// transposed split Tp (plane stride M*N). ----
__global__ __launch_bounds__(256, 2) void k_gemm_x6_bt(const unsigned short* __restrict__ As,
    size_t APS, const unsigned short* __restrict__ BTs, size_t BPS, float* __restrict__ C,
    unsigned short* __restrict__ Tp, int M, int N, int K) {
  __shared__ __align__(16) unsigned short Ai[3][128 * 40];
  __shared__ __align__(16) unsigned short Bj[3][128 * 40];
  int tid = threadIdx.x;
  int m0 = blockIdx.y << 7, n0 = blockIdx.x << 7;
  int lane = tid & 63, w = tid >> 6;
  int lr = lane & 15, kb = lane >> 4;
  int wr = (w >> 1) << 6, wc = (w & 1) << 6;
  int sr = tid >> 1, sc = (tid & 1) << 4;
  uint4 rA[3][2], rB[3][2];
  auto load_k = [&](int k0) {
#pragma unroll
    for (int p = 0; p < 3; ++p) {
      const unsigned short* ga = &As[p * APS + (size_t)(m0 + sr) * K + k0 + sc];
      rA[p][0] = *reinterpret_cast<const uint4*>(ga);
      rA[p][1] = *reinterpret_cast<const uint4*>(ga + 8);
      const unsigned short* gb = &BTs[p * BPS + (size_t)(n0 + sr) * K + k0 + sc];
      rB[p][0] = *reinterpret_cast<const uint4*>(gb);
      rB[p][1] = *reinterpret_cast<const uint4*>(gb + 8);
    }
  };
  load_k(0);
  f32x4 acc[4][4] = {};
  for (int k0 = 0; k0 < K; k0 += 32) {
    __syncthreads();
#pragma unroll
    for (int p = 0; p < 3; ++p) {
      *reinterpret_cast<uint4*>(&Ai[p][sr * 40 + sc]) = rA[p][0];
      *reinterpret_cast<uint4*>(&Ai[p][sr * 40 + sc + 8]) = rA[p][1];
      *reinterpret_cast<uint4*>(&Bj[p][sr * 40 + sc]) = rB[p][0];
      *reinterpret_cast<uint4*>(&Bj[p][sr * 40 + sc + 8]) = rB[p][1];
    }
    __syncthreads();
    if (k0 + 32 < K) load_k(k0 + 32);
    bf16x8 af[4][3], bf_[4][3];
#pragma unroll
    for (int m = 0; m < 4; ++m)
#pragma unroll
      for (int p = 0; p < 3; ++p)
        af[m][p] = *reinterpret_cast<const bf16x8*>(&Ai[p][(wr + m * 16 + lr) * 40 + kb * 8]);
#pragma unroll
    for (int n = 0; n < 4; ++n)
#pragma unroll
      for (int p = 0; p < 3; ++p)
        bf_[n][p] = *reinterpret_cast<const bf16x8*>(&Bj[p][(wc + n * 16 + lr) * 40 + kb * 8]);
#pragma unroll
    for (int m = 0; m < 4; ++m)
#pragma unroll
      for (int n = 0; n < 4; ++n) {
        acc[m][n] = __builtin_amdgcn_mfma_f32_16x16x32_bf16(af[m][0], bf_[n][0], acc[m][n], 0, 0, 0);
        acc[m][n] = __builtin_amdgcn_mfma_f32_16x16x32_bf16(af[m][0], bf_[n][1], acc[m][n], 0, 0, 0);
        acc[m][n] = __builtin_amdgcn_mfma_f32_16x16x32_bf16(af[m][1], bf_[n][0], acc[m][n], 0, 0, 0);
        acc[m][n] = __builtin_amdgcn_mfma_f32_16x16x32_bf16(af[m][0], bf_[n][2], acc[m][n], 0, 0, 0);
        acc[m][n] = __builtin_amdgcn_mfma_f32_16x16x32_bf16(af[m][2], bf_[n][0], acc[m][n], 0, 0, 0);
        acc[m][n] = __builtin_amdgcn_mfma_f32_16x16x32_bf16(af[m][1], bf_[n][1], acc[m][n], 0, 0, 0);
      }
  }
  int orow = m0 + wr + (lane >> 4) * 4;
  int ocol = n0 + wc + lr;
  size_t TPS = (size_t)M * N;
#pragma unroll
  for (int m = 0; m < 4; ++m)
#pragma unroll
    for (int n = 0; n < 4; ++n) {
      int cn = ocol + n * 16, rw = orow + m * 16;
#pragma unroll
      for (int r = 0; r < 4; ++r) C[(size_t)(rw + r) * N + cn] = acc[m][n][r];
      if (Tp) {
        unsigned short o1[4], o2[4], o3[4];
#pragma unroll
        for (int r = 0; r < 4; ++r) {
          float x = acc[m][n][r];
          unsigned short a = f2b(x);
          float r1 = x - b2f(a);
          unsigned short b = f2b(r1);
          float r2 = r1 - b2f(b);
          o1[r] = a; o2[r] = b; o3[r] = f2b(r2);
        }
        size_t tb = (size_t)cn * M + rw;
        *reinterpret_cast<uint2*>(&Tp[tb]) = *reinterpret_cast<const uint2*>(o1);
        *reinterpret_cast<uint2*>(&Tp[TPS + tb]) = *reinterpret_cast<const uint2*>(o2);
        *reinterpret_cast<uint2*>(&Tp[2 * TPS + tb]) = *reinterpret_cast<const uint2*>(o3);
      }
    }
}

// ---- bf16x6 GAT aggregation v5: reg-prefetch, 2 barriers/tile, 2 blocks/CU ----
__global__ __launch_bounds__(512, 4) void k_gat_x6(const float* __restrict__ Adj, int N,
    const unsigned short* __restrict__ XpS, size_t PS,
    const float* __restrict__ src, const float* __restrict__ dst,
    float* __restrict__ P, float* __restrict__ dP, int HF, int Ffull, int FP, int jchunk) {
  __shared__ __align__(16) unsigned short wL[3][128 * 40];
  __shared__ __align__(16) unsigned short xL[3][128 * 40];
  __shared__ float dstL[128];
  __shared__ float srcL[2][32];
  int H = HF / Ffull;
  int h = blockIdx.x / FP;
  int fp = blockIdx.x % FP;
  int f0 = fp << 7;
  int i0 = blockIdx.y << 7;
  int jb0 = blockIdx.z * jchunk;
  int tid = threadIdx.x;
  int si = tid >> 2, sj8 = (tid & 3) << 3;
  int lane = tid & 63, w = tid >> 6;
  int lr = lane & 15, kb = lane >> 4;
  int fs = w << 4;
  if (tid < 128) dstL[tid] = dst[(i0 + tid) * H + h];
  if (tid < 32) srcL[0][tid] = src[(jb0 + tid) * H + h];
  const unsigned short* xbase = XpS + ((size_t)h * Ffull + f0) * N;
  float4 av0, av1;
  uint4 xv[3];
  auto load_tile = [&](int jb) {
    av0 = *reinterpret_cast<const float4*>(&Adj[(size_t)(i0 + si) * N + jb + sj8]);
    av1 = *reinterpret_cast<const float4*>(&Adj[(size_t)(i0 + si) * N + jb + sj8 + 4]);
#pragma unroll
    for (int p = 0; p < 3; ++p)
      xv[p] = *reinterpret_cast<const uint4*>(&xbase[p * PS + (size_t)si * N + jb + sj8]);
  };
  load_tile(jb0);
  float dsum = 0.f;
  f32x4 acc[8] = {};
  int ntiles = jchunk >> 5;
  for (int t = 0; t < ntiles; ++t) {
    int jb = jb0 + (t << 5);
    int cur = t & 1;
    __syncthreads();  // prev MFMA done; srcL[cur] ready
    {
      int gi = i0 + si;
      float dq = dstL[si];
      const float* a0 = (const float*)&av0;
      const float* a1 = (const float*)&av1;
      unsigned short h1[8], h2[8], h3[8];
      float ds = 0.f;
#pragma unroll
      for (int e = 0; e < 8; ++e) {
        float a = e < 4 ? a0[e] : a1[e - 4];
        float wv = 0.f;
        if (a != 0.f || (jb + sj8 + e) == gi) {
          float tt = dq + srcL[cur][sj8 + e];
          tt = tt >= 0.f ? tt : 0.2f * tt;
          wv = __expf(tt);
        }
        ds += wv;
        unsigned u1 = __float_as_uint(wv);
        h1[e] = (unsigned short)(u1 >> 16);
        float r1 = wv - __uint_as_float(u1 & 0xffff0000u);
        unsigned u2 = __float_as_uint(r1);
        h2[e] = (unsigned short)(u2 >> 16);
        float r2 = r1 - __uint_as_float(u2 & 0xffff0000u);
        h3[e] = (unsigned short)(__float_as_uint(r2) >> 16);
      }
      dsum += ds;
      *reinterpret_cast<uint4*>(&wL[0][si * 40 + sj8]) = *reinterpret_cast<const uint4*>(h1);
      *reinterpret_cast<uint4*>(&wL[1][si * 40 + sj8]) = *reinterpret_cast<const uint4*>(h2);
      *reinterpret_cast<uint4*>(&wL[2][si * 40 + sj8]) = *reinterpret_cast<const uint4*>(h3);
#pragma unroll
      for (int p = 0; p < 3; ++p)
        *reinterpret_cast<uint4*>(&xL[p][si * 40 + sj8]) = xv[p];
    }
    __syncthreads();  // staged
    if (t + 1 < ntiles) {
      int jn = jb + 32;
      if (tid < 32) srcL[cur ^ 1][tid] = src[(jn + tid) * H + h];
      load_tile(jn);
    }
    bf16x8 bf_[3];
#pragma unroll
    for (int p = 0; p < 3; ++p)
      bf_[p] = *reinterpret_cast<const bf16x8*>(&xL[p][(fs + lr) * 40 + kb * 8]);
#pragma unroll
    for (int m = 0; m < 8; ++m) {
      bf16x8 af[3];
#pragma unroll
      for (int p = 0; p < 3; ++p)
        af[p] = *reinterpret_cast<const bf16x8*>(&wL[p][(m * 16 + lr) * 40 + kb * 8]);
      acc[m] = __builtin_amdgcn_mfma_f32_16x16x32_bf16(af[0], bf_[0], acc[m], 0, 0, 0);
      acc[m] = __builtin_amdgcn_mfma_f32_16x16x32_bf16(af[0], bf_[1], acc[m], 0, 0, 0);
      acc[m] = __builtin_amdgcn_mfma_f32_16x16x32_bf16(af[1], bf_[0], acc[m], 0, 0, 0);
      acc[m] = __builtin_amdgcn_mfma_f32_16x16x32_bf16(af[0], bf_[2], acc[m], 0, 0, 0);
      acc[m] = __builtin_amdgcn_mfma_f32_16x16x32_bf16(af[2], bf_[0], acc[m], 0, 0, 0);
      acc[m] = __builtin_amdgcn_mfma_f32_16x16x32_bf16(af[1], bf_[1], acc[m], 0, 0, 0);
    }
  }
  if (fp == 0) {
    float v = dsum;
    v += __shfl_xor(v, 1);
    v += __shfl_xor(v, 2);
    if ((tid & 3) == 0)
      dP[(size_t)blockIdx.z * N * H + (i0 + si) * H + h] = v;
  }
  float* Pc = P + (size_t)blockIdx.z * N * HF;
  int orow = i0 + (lane >> 4) * 4;
  int ocol = h * Ffull + f0 + fs + lr;
#pragma unroll
  for (int m = 0; m < 8; ++m)
#pragma unroll
    for (int r = 0; r < 4; ++r)
      Pc[(size_t)(orow + m * 16 + r) * HF + ocol] = acc[m][r];
}

// ---- unified multi-head bf16 GAT v2 (reg-prefetch) ----
template <int NS, int HEADS>
__global__ __launch_bounds__(512, 4) void k_gat_b16(const float* __restrict__ Adj, int N,
    const unsigned short* __restrict__ XpT,
    const float* __restrict__ src, const float* __restrict__ dst,
    float* __restrict__ P, float* __restrict__ dP, int HF, int F, int jchunk) {
  constexpr int HFB = NS * 128;
  __shared__ __align__(16) unsigned short wL[HEADS][128 * 40];
  __shared__ __align__(16) unsigned short xL[HFB * 40];
  __shared__ float dstL[HEADS][128];
  __shared__ float srcL[2][HEADS][32];
  int H = HF / F;
  int hf0 = blockIdx.x * HFB;
  int h0 = hf0 / F;
  int i0 = blockIdx.y << 7;
  int jb0 = blockIdx.z * jchunk;
  int tid = threadIdx.x;
  int si = tid >> 2, sj8 = (tid & 3) << 3;
  int lane = tid & 63, w = tid >> 6;
  int lr = lane & 15, kb = lane >> 4;
  int fs = w * (NS * 16);
  int hw = (hf0 + fs) / F - h0;
  if (tid < HEADS * 128)
    dstL[tid >> 7][tid & 127] = dst[(i0 + (tid & 127)) * H + h0 + (tid >> 7)];
  if (tid < HEADS * 32)
    srcL[0][tid >> 5][tid & 31] = src[(jb0 + (tid & 31)) * H + h0 + (tid >> 5)];
  float4 av0, av1;
  uint4 xv[NS];
  auto load_tile = [&](int jb) {
    av0 = *reinterpret_cast<const float4*>(&Adj[(size_t)(i0 + si) * N + jb + sj8]);
    av1 = *reinterpret_cast<const float4*>(&Adj[(size_t)(i0 + si) * N + jb + sj8 + 4]);
#pragma unroll
    for (int s = 0; s < NS; ++s)
      xv[s] = *reinterpret_cast<const uint4*>(
          &XpT[(size_t)(hf0 + s * 128 + si) * N + jb + sj8]);
  };
  load_tile(jb0);
  float dsum[HEADS] = {};
  f32x4 acc[8][NS] = {};
  int ntiles = jchunk >> 5;
  for (int t = 0; t < ntiles; ++t) {
    int jb = jb0 + (t << 5);
    int cur = t & 1;
    __syncthreads();
    {
      int gi = i0 + si;
      const float* a0 = (const float*)&av0;
      const float* a1 = (const float*)&av1;
#pragma unroll
      for (int hh = 0; hh < HEADS; ++hh) {
        float dq = dstL[hh][si];
        unsigned short wb[8];
        float ds = 0.f;
#pragma unroll
        for (int e = 0; e < 8; ++e) {
          float a = e < 4 ? a0[e] : a1[e - 4];
          float wv = 0.f;
          if (a != 0.f || (jb + sj8 + e) == gi) {
            float tt = dq + srcL[cur][hh][sj8 + e];
            tt = tt >= 0.f ? tt : 0.2f * tt;
            wv = __expf(tt);
          }
          ds += wv;
          wb[e] = f2b(wv);
        }
        dsum[hh] += ds;
        *reinterpret_cast<uint4*>(&wL[hh][si * 40 + sj8]) = *reinterpret_cast<const uint4*>(wb);
      }
#pragma unroll
      for (int s = 0; s < NS; ++s)
        *reinterpret_cast<uint4*>(&xL[(s * 128 + si) * 40 + sj8]) = xv[s];
    }
    __syncthreads();
    if (t + 1 < ntiles) {
      int jn = jb + 32;
      if (tid < HEADS * 32)
        srcL[cur ^ 1][tid >> 5][tid & 31] = src[(jn + (tid & 31)) * H + h0 + (tid >> 5)];
      load_tile(jn);
    }
    bf16x8 bf_[NS];
#pragma unroll
    for (int n = 0; n < NS; ++n)
      bf_[n] = *reinterpret_cast<const bf16x8*>(&xL[(fs + n * 16 + lr) * 40 + kb * 8]);
#pragma unroll
    for (int m = 0; m < 8; ++m) {
      bf16x8 a = *reinterpret_cast<const bf16x8*>(&wL[hw][(m * 16 + lr) * 40 + kb * 8]);
#pragma unroll
      for (int n = 0; n < NS; ++n)
        acc[m][n] = __builtin_amdgcn_mfma_f32_16x16x32_bf16(a, bf_[n], acc[m][n], 0, 0, 0);
    }
  }
#pragma unroll
  for (int hh = 0; hh < HEADS; ++hh) {
    float v = dsum[hh];
    v += __shfl_xor(v, 1);
    v += __shfl_xor(v, 2);
    if ((tid & 3) == 0)
      dP[(size_t)blockIdx.z * N * H + (i0 + si) * H + h0 + hh] = v;
  }
  float* Pc = P + (size_t)blockIdx.z * N * HF;
  int orow = i0 + (lane >> 4) * 4;
  int ocol0 = hf0 + fs + lr;
#pragma unroll
  for (int m = 0; m < 8; ++m)
#pragma unroll
    for (int n = 0; n < NS; ++n)
#pragma unroll
      for (int r = 0; r < 4; ++r)
        Pc[(size_t)(orow + m * 16 + r) * HF + ocol0 + n * 16] = acc[m][n][r];
}

// Out = relu((sum_c P[c]) / (sum_c dP[c]) + bias); optional f32/bf16 outputs
__global__ void k_gat_reduce(const float* __restrict__ P, int nch, size_t chstride,
    const float* __restrict__ dP, size_t dstride, const float* __restrict__ bias,
    float* __restrict__ Of, unsigned short* __restrict__ Ob, int HF, int F, int n_total) {
  int e = (blockIdx.x * 256 + threadIdx.x) * 4;
  if (e >= n_total) return;
  float4 s = *reinterpret_cast<const float4*>(&P[e]);
  for (int c = 1; c < nch; ++c) {
    float4 v = *reinterpret_cast<const float4*>(&P[c * chstride + e]);
    s.x += v.x; s.y += v.y; s.z += v.z; s.w += v.w;
  }
  int i = e / HF;
  int hf = e - i * HF;
  int h = hf / F;
  float den = 0.f;
  for (int c = 0; c < nch; ++c) den += dP[c * dstride + i * (HF / F) + h];
  float inv = 1.f / den;
  float4 bz = *reinterpret_cast<const float4*>(&bias[hf]);
  float4 o;
  o.x = fmaxf(fmaf(s.x, inv, bz.x), 0.f);
  o.y = fmaxf(fmaf(s.y, inv, bz.y), 0.f);
  o.z = fmaxf(fmaf(s.z, inv, bz.z), 0.f);
  o.w = fmaxf(fmaf(s.w, inv, bz.w), 0.f);
  if (Of) *reinterpret_cast<float4*>(&Of[e]) = o;
  if (Ob) {
    unsigned short ob[4] = {f2b(o.x), f2b(o.y), f2b(o.z), f2b(o.w)};
    *reinterpret_cast<uint2*>(&Ob[e]) = *reinterpret_cast<const uint2*>(ob);
  }
}

// ---- bf16 MFMA: C = relu(G @ G^T), triangular + mirror ----
__global__ __launch_bounds__(256) void k_syrk_mfma(const unsigned short* __restrict__ G,
    int M, int Kd, float* __restrict__ C) {
  if (blockIdx.x < blockIdx.y) return;
  __shared__ __align__(16) unsigned short Ai[128 * 40];
  __shared__ __align__(16) unsigned short Bj[128 * 40];
  int tid = threadIdx.x;
  int i0 = blockIdx.y << 7, j0 = blockIdx.x << 7;
  int srow = tid >> 1, scol = (tid & 1) << 3;
  int lane = tid & 63, w = tid >> 6;
  int wr = (w >> 1) << 6, wc = (w & 1) << 6;
  int lr = lane & 15, kb = lane >> 4;
  f32x4 acc[4][4] = {};
  const unsigned short* gA = G + (size_t)i0 * Kd;
  const unsigned short* gB = G + (size_t)j0 * Kd;
  for (int k0 = 0; k0 < Kd; k0 += 32) {
    __syncthreads();
#pragma unroll
    for (int kk = 0; kk < 32; kk += 16) {
      *reinterpret_cast<uint4*>(&Ai[srow * 40 + scol + kk]) =
          *reinterpret_cast<const uint4*>(&gA[(size_t)srow * Kd + k0 + scol + kk]);
      *reinterpret_cast<uint4*>(&Bj[srow * 40 + scol + kk]) =
          *reinterpret_cast<const uint4*>(&gB[(size_t)srow * Kd + k0 + scol + kk]);
    }
    __syncthreads();
    bf16x8 a[4], b[4];
#pragma unroll
    for (int m = 0; m < 4; ++m)
      a[m] = *reinterpret_cast<const bf16x8*>(&Ai[(wr + m * 16 + lr) * 40 + kb * 8]);
#pragma unroll
    for (int n = 0; n < 4; ++n)
      b[n] = *reinterpret_cast<const bf16x8*>(&Bj[(wc + n * 16 + lr) * 40 + kb * 8]);
#pragma unroll
    for (int m = 0; m < 4; ++m)
#pragma unroll
      for (int n = 0; n < 4; ++n)
        acc[m][n] = __builtin_amdgcn_mfma_f32_16x16x32_bf16(a[m], b[n], acc[m][n], 0, 0, 0);
  }
  int orow = i0 + wr + (lane >> 4) * 4;
  int ocol = j0 + wc + (lane & 15);
  bool mirror = (j0 != i0);
#pragma unroll
  for (int m = 0; m < 4; ++m)
#pragma unroll
    for (int n = 0; n < 4; ++n) {
      float4 v;
      v.x = fmaxf(acc[m][n][0], 0.f);
      v.y = fmaxf(acc[m][n][1], 0.f);
      v.z = fmaxf(acc[m][n][2], 0.f);
      v.w = fmaxf(acc[m][n][3], 0.f);
#pragma unroll
      for (int r = 0; r < 4; ++r)
        C[(size_t)(orow + m * 16 + r) * M + ocol + n * 16] = ((const float*)&v)[r];
      if (mirror)
        *reinterpret_cast<float4*>(
            &C[(size_t)(j0 + wc + n * 16 + lr) * M + i0 + wr + m * 16 + (lane >> 4) * 4]) = v;
    }
}

// C = A @ BT^T (+bias), reg-prefetch; optional transposed bf16 out Tp[col*M+row].
__global__ __launch_bounds__(256) void k_gemm_mfma_bt(const unsigned short* __restrict__ Amat,
    const unsigned short* __restrict__ BT, const float* __restrict__ bias,
    float* __restrict__ C, unsigned short* __restrict__ Tp, int M, int N, int Kd) {
  __shared__ __align__(16) unsigned short Ai[128 * 40];
  __shared__ __align__(16) unsigned short Bj[128 * 40];
  int tid = threadIdx.x;
  int m0 = blockIdx.y << 7, n0 = blockIdx.x << 7;
  int srow = tid >> 1, scol = (tid & 1) << 3;
  int lane = tid & 63, w = tid >> 6;
  int wr = (w >> 1) << 6, wc = (w & 1) << 6;
  int lr = lane & 15, kb = lane >> 4;
  uint4 rA[2], rB[2];
  auto load_k = [&](int k0) {
    const unsigned short* ga = &Amat[(size_t)(m0 + srow) * Kd + k0 + scol];
    rA[0] = *reinterpret_cast<const uint4*>(ga);
    rA[1] = *reinterpret_cast<const uint4*>(ga + 16);
    const unsigned short* gb = &BT[(size_t)(n0 + srow) * Kd + k0 + scol];
    rB[0] = *reinterpret_cast<const uint4*>(gb);
    rB[1] = *reinterpret_cast<const uint4*>(gb + 16);
  };
  load_k(0);
  f32x4 acc[4][4] = {};
  for (int k0 = 0; k0 < Kd; k0 += 32) {
    __syncthreads();
    *reinterpret_cast<uint4*>(&Ai[srow * 40 + scol]) = rA[0];
    *reinterpret_cast<uint4*>(&Ai[srow * 40 + scol + 16]) = rA[1];
    *reinterpret_cast<uint4*>(&Bj[srow * 40 + scol]) = rB[0];
    *reinterpret_cast<uint4*>(&Bj[srow * 40 + scol + 16]) = rB[1];
    __syncthreads();
    if (k0 + 32 < Kd) load_k(k0 + 32);
    bf16x8 a[4], b[4];
#pragma unroll
    for (int m = 0; m < 4; ++m)
      a[m] = *reinterpret_cast<const bf16x8*>(&Ai[(wr + m * 16 + lr) * 40 + kb * 8]);
#pragma unroll
    for (int n = 0; n < 4; ++n)
      b[n] = *reinterpret_cast<const bf16x8*>(&Bj[(wc + n * 16 + lr) * 40 + kb * 8]);
#pragma unroll
    for (int m = 0; m < 4; ++m)
#pragma unroll
      for (int n = 0; n < 4; ++n)
        acc[m][n] = __builtin_amdgcn_mfma_f32_16x16x32_bf16(a[m], b[n], acc[m][n], 0, 0, 0);
  }
  int orow = m0 + wr + (lane >> 4) * 4;
  int ocol = n0 + wc + lr;
#pragma unroll
  for (int m = 0; m < 4; ++m)
#pragma unroll
    for (int n = 0; n < 4; ++n) {
      int cn = ocol + n * 16, rw = orow + m * 16;
#pragma unroll
      for (int r = 0; r < 4; ++r) {
        float rb = bias ? bias[rw + r] : 0.f;
        C[(size_t)(rw + r) * N + cn] = acc[m][n][r] + rb;
      }
      if (Tp) {
        unsigned short o[4] = {f2b(acc[m][n][0]), f2b(acc[m][n][1]), f2b(acc[m][n][2]),
                               f2b(acc[m][n][3])};
        *reinterpret_cast<uint2*>(&Tp[(size_t)cn * M + rw]) =
            *reinterpret_cast<const uint2*>(o);
      }
    }
}

// ---- upsampler GEMM: split-k 8, reg-prefetch ----
__global__ __launch_bounds__(512) void k_gemm_aup(const float* __restrict__ Wg,
    const unsigned short* __restrict__ BT, float* __restrict__ Pz, int Mtot, int Ktot,
    int kc_len) {
  __shared__ __align__(16) unsigned short Ai[128 * 40];
  __shared__ __align__(16) unsigned short Bj[256 * 40];
  int tid = threadIdx.x;
  int m0 = blockIdx.y << 7;
  int k0base = blockIdx.x * kc_len;
  int lane = tid & 63, w = tid >> 6;
  int wr = (w >> 2) << 6, wc = (w & 3) << 6;
  int lr = lane & 15, kb = lane >> 4;
  int ar = tid >> 2, ac8 = (tid & 3) << 3;
  int br = tid >> 1, bc16 = (tid & 1) << 4;
  float4 ra0, ra1;
  uint4 rb0, rb1;
  auto load_k = [&](int k0) {
    const float* arow = &Wg[(size_t)(m0 + ar) * Ktot + k0 + ac8];
    ra0 = *reinterpret_cast<const float4*>(arow);
    ra1 = *reinterpret_cast<const float4*>(arow + 4);
    const unsigned short* brow = &BT[(size_t)br * Ktot + k0 + bc16];
    rb0 = *reinterpret_cast<const uint4*>(brow);
    rb1 = *reinterpret_cast<const uint4*>(brow + 8);
  };
  load_k(k0base);
  f32x4 acc[4][4] = {};
  for (int kk = 0; kk < kc_len; kk += 32) {
    __syncthreads();
    {
      unsigned short t8[8] = {f2b(ra0.x), f2b(ra0.y), f2b(ra0.z), f2b(ra0.w),
                              f2b(ra1.x), f2b(ra1.y), f2b(ra1.z), f2b(ra1.w)};
      *reinterpret_cast<uint4*>(&Ai[ar * 40 + ac8]) = *reinterpret_cast<const uint4*>(t8);
      *reinterpret_cast<uint4*>(&Bj[br * 40 + bc16]) = rb0;
      *reinterpret_cast<uint4*>(&Bj[br * 40 + bc16 + 8]) = rb1;
    }
    __syncthreads();
    if (kk + 32 < kc_len) load_k(k0base + kk + 32);
    bf16x8 a[4], b[4];
#pragma unroll
    for (int m = 0; m < 4; ++m)
      a[m] = *reinterpret_cast<const bf16x8*>(&Ai[(wr + m * 16 + lr) * 40 + kb * 8]);
#pragma unroll
    for (int n = 0; n < 4; ++n)
      b[n] = *reinterpret_cast<const bf16x8*>(&Bj[(wc + n * 16 + lr) * 40 + kb * 8]);
#pragma unroll
    for (int m = 0; m < 4; ++m)
#pragma unroll
      for (int n = 0; n < 4; ++n)
        acc[m][n] = __builtin_amdgcn_mfma_f32_16x16x32_bf16(a[m], b[n], acc[m][n], 0, 0, 0);
  }
  float* outp = Pz + (size_t)blockIdx.x * Mtot * 256;
  int orow = m0 + wr + (lane >> 4) * 4;
  int ocol = wc + (lane & 15);
#pragma unroll
  for (int m = 0; m < 4; ++m)
#pragma unroll
    for (int n = 0; n < 4; ++n)
#pragma unroll
      for (int r = 0; r < 4; ++r)
        outp[(size_t)(orow + m * 16 + r) * 256 + ocol + n * 16] = acc[m][n][r];
}

// row softmax over 256 cols of (sum_c Pz[c] + bias[row]) -> bf16
__global__ __launch_bounds__(256) void k_softmax_fuse(const float* __restrict__ Pz, int nch,
    size_t chstride, const float* __restrict__ bias, unsigned short* __restrict__ ZB) {
  int row = blockIdx.x, tid = threadIdx.x;
  size_t e = (size_t)row * 256 + tid;
  float x = bias[row];
  for (int c = 0; c < nch; ++c) x += Pz[c * chstride + e];
  float m = x;
#pragma unroll
  for (int off = 32; off; off >>= 1) m = fmaxf(m, __shfl_down(m, off));
  __shared__ float red[4];
  __shared__ float bm, bs;
  if ((tid & 63) == 0) red[tid >> 6] = m;
  __syncthreads();
  if (tid == 0) bm = fmaxf(fmaxf(red[0], red[1]), fmaxf(red[2], red[3]));
  __syncthreads();
  float ev = expf(x - bm);
  float sm = wave_sum64(ev);
  __syncthreads();
  if ((tid & 63) == 0) red[tid >> 6] = sm;
  __syncthreads();
  if (tid == 0) bs = red[0] + red[1] + red[2] + red[3];
  __syncthreads();
  ZB[e] = f2b(ev / bs);
}

// src[n,h] = sum_f Xp[n,h,f]*a_src[h,f]; dst likewise.
__global__ void k_src_dst(const float* __restrict__ Xp, const float* __restrict__ a_src,
    const float* __restrict__ a_dst, float* __restrict__ src, float* __restrict__ dst,
    int H, int F) {
  int n = blockIdx.x;
  int h = threadIdx.x >> 6, lane = threadIdx.x & 63;
  const float* x = Xp + ((size_t)n * H + h) * F;
  const float* as = a_src + h * F;
  const float* ad = a_dst + h * F;
  float ps = 0.f, pd = 0.f;
  for (int f = lane; f < F; f += 64) {
    float xv = x[f];
    ps = fmaf(xv, as[f], ps);
    pd = fmaf(xv, ad[f], pd);
  }
  ps = wave_sum64(ps);
  pd = wave_sum64(pd);
  if (lane == 0) { src[n * H + h] = ps; dst[n * H + h] = pd; }
}

// s[row] = sigmoid(dot(X[row,:], w) + b)
__global__ __launch_bounds__(256) void k_score(const float* __restrict__ Xf,
    const float* __restrict__ wv, const float* __restrict__ bsc, float* __restrict__ s, int D) {
  int row = blockIdx.x * 4 + (threadIdx.x >> 6);
  int lane = threadIdx.x & 63;
  const float* x = Xf + (size_t)row * D;
  float p = 0.f;
  for (int f = lane; f < D; f += 64) p = fmaf(x[f], wv[f], p);
  p = wave_sum64(p);
  if (lane == 0) s[row] = 1.f / (1.f + expf(-(p + bsc[0])));
}

// top-k by exact rank counting; emits idx/vals + inverse rank map (0 = unselected).
__global__ __launch_bounds__(256) void k_topk_rank(const float* __restrict__ s, int n, int k,
    int* __restrict__ idx, float* __restrict__ vals, int* __restrict__ inv) {
  extern __shared__ unsigned long long keys[];
  int tid = threadIdx.x;
  int i = blockIdx.x * 256 + tid;
  for (int j = tid; j < n; j += 256) {
    unsigned u = __float_as_uint(s[j]);
    unsigned ord = (u & 0x80000000u) ? ~u : (u | 0x80000000u);
    keys[j] = ((unsigned long long)ord << 32) | (unsigned)(~j);
  }
  __syncthreads();
  unsigned long long mykey = keys[i];
  int rank = 0;
#pragma unroll 4
  for (int j = 0; j < n; ++j) rank += (keys[j] > mykey);
  int sel = rank < k;
  inv[i] = sel ? rank + 1 : 0;
  if (sel) {
    idx[rank] = i;
    vals[rank] = s[i];
  }
}

// sv[i] = rsqrt(dot(A0[idx[i],:], selected-mask) + 1e-5)
__global__ __launch_bounds__(256) void k_rowsum_mask(const float* __restrict__ A0, int N,
    const int* __restrict__ idx, const int* __restrict__ inv, float* __restrict__ sv) {
  int i = blockIdx.x, tid = threadIdx.x;
  const float* row = A0 + (size_t)idx[i] * N;
  float p = 0.f;
  for (int j = tid * 4; j < N; j += 1024) {
    float4 a = *reinterpret_cast<const float4*>(&row[j]);
    int4 b = *reinterpret_cast<const int4*>(&inv[j]);
    if (b.x) p += a.x;
    if (b.y) p += a.y;
    if (b.z) p += a.z;
    if (b.w) p += a.w;
  }
  p = wave_sum64(p);
  __shared__ float red[4];
  if ((tid & 63) == 0) red[tid >> 6] = p;
  __syncthreads();
  if (tid == 0) sv[i] = rsqrtf(red[0] + red[1] + red[2] + red[3] + 1e-5f);
}

// T1[c][i] = A0[idx[i]][c]
__global__ __launch_bounds__(256) void k_gatherT(const float* __restrict__ A0, int N,
    const int* __restrict__ idx, float* __restrict__ T1, int k) {
  __shared__ float T[64][65];
  int i0 = blockIdx.x << 6, c0 = blockIdx.y << 6;
  int tid = threadIdx.x;
  int tr = tid >> 4, tc4 = (tid & 15) << 2;
#pragma unroll
  for (int q = 0; q < 4; ++q) {
    int row = tr + q * 16;
    float4 v = *reinterpret_cast<const float4*>(&A0[(size_t)idx[i0 + row] * N + c0 + tc4]);
    T[tc4 + 0][row] = v.x; T[tc4 + 1][row] = v.y; T[tc4 + 2][row] = v.z; T[tc4 + 3][row] = v.w;
  }
  __syncthreads();
#pragma unroll
  for (int q = 0; q < 4; ++q) {
    int row = tr + q * 16;
    float4 o;
    o.x = T[row][tc4]; o.y = T[row][tc4 + 1]; o.z = T[row][tc4 + 2]; o.w = T[row][tc4 + 3];
    *reinterpret_cast<float4*>(&T1[(size_t)(c0 + row) * k + i0 + tc4]) = o;
  }
}

// A1[j][i] = T1[idx[j]][i] * sv[j] * sv[i]
__global__ void k_scaleT(const float* __restrict__ T1, int k, const int* __restrict__ idx,
    const float* __restrict__ sv, float* __restrict__ A1) {
  int j = blockIdx.y;
  int i = (blockIdx.x * 256 + threadIdx.x) * 4;
  float sj = sv[j];
  const float* r = T1 + (size_t)idx[j] * k;
  float4 v = *reinterpret_cast<const float4*>(&r[i]);
  float4 s = *reinterpret_cast<const float4*>(&sv[i]);
  v.x *= sj * s.x; v.y *= sj * s.y; v.z *= sj * s.z; v.w *= sj * s.w;
  *reinterpret_cast<float4*>(&A1[(size_t)j * k + i]) = v;
}

__global__ void k_gather_mat(const float* __restrict__ Asrc, int lda,
    const int* __restrict__ idx, float* __restrict__ B, int k) {
  int j = blockIdx.x * 256 + threadIdx.x;
  int i = blockIdx.y;
  B[(size_t)i * k + j] = Asrc[(size_t)idx[i] * lda + idx[j]];
}

// Xo[node] = inv[node] ? P[inv[node]-1] : 0  (single-pass unpool)
__global__ void k_unpool(const float* __restrict__ Pn, int Dd, const int* __restrict__ inv,
                         float* __restrict__ Xo) {
  int node = blockIdx.y;
  int f = blockIdx.x * 256 + threadIdx.x;
  int r = inv[node];
  Xo[(size_t)node * Dd + f] = r ? Pn[(size_t)(r - 1) * Dd + f] : 0.f;
}

extern "C" void kernel_launch(void* const* d_in, const int* in_sizes, int n_in,
                              void* d_out, int out_size, void* d_ws, size_t ws_size,
                              hipStream_t stream) {
  const float* A    = (const float*)d_in[0];
  const float* X    = (const float*)d_in[1];
  const float* Wd0  = (const float*)d_in[2];
  const float* asd0 = (const float*)d_in[3];
  const float* add0 = (const float*)d_in[4];
  const float* bd0  = (const float*)d_in[5];
  const float* Wd1  = (const float*)d_in[6];
  const float* asd1 = (const float*)d_in[7];
  const float* add1 = (const float*)d_in[8];
  const float* bd1  = (const float*)d_in[9];
  const float* wp0  = (const float*)d_in[10];
  const float* bp0  = (const float*)d_in[11];
  const float* wp1  = (const float*)d_in[12];
  const float* bp1  = (const float*)d_in[13];
  const float* Wb   = (const float*)d_in[14];
  const float* asb  = (const float*)d_in[15];
  const float* adb  = (const float*)d_in[16];
  const float* bb   = (const float*)d_in[17];
  const float* Wu0  = (const float*)d_in[18];
  const float* asu0 = (const float*)d_in[19];
  const float* adu0 = (const float*)d_in[20];
  const float* bu0  = (const float*)d_in[21];
  const float* Wu1  = (const float*)d_in[22];
  const float* asu1 = (const float*)d_in[23];
  const float* adu1 = (const float*)d_in[24];
  const float* bu1  = (const float*)d_in[25];
  const float* Wup  = (const float*)d_in[26];
  const float* bup  = (const float*)d_in[27];
  (void)in_sizes; (void)n_in; (void)out_size; (void)ws_size;

  float* out  = (float*)d_out;
  float* Aup  = out;                    // [8192*8192]
  float* A0   = out + 67108864ULL;      // [4096*4096]
  float* A1   = A0 + 16777216ULL;       // [2048*2048]
  float* rec0 = A1 + 4194304ULL;        // [2048*2048]
  float* rec1 = rec0 + 4194304ULL;      // [4096*4096]

  // Scratch in the A_up output region (dead before A_up syrk writes).
  float* S = Aup;
  size_t off = 0;
  auto nxt = [&](size_t n) { float* p = S + off; off += (n + 1023) & ~(size_t)1023; return p; };
  float* Xp0  = nxt(4096 * 512);
  float* X0   = nxt(4096 * 512);
  float* src0 = nxt(4096 * 4);
  float* dst0 = nxt(4096 * 4);
  float* sc0  = nxt(4096);
  int*   idx0 = (int*)nxt(2048);
  float* v0   = nxt(2048);
  float* sv0  = nxt(2048);
  int*   inv0 = (int*)nxt(4096);
  float* Xp1  = nxt(2048 * 1024);
  float* X1   = nxt(2048 * 1024);
  float* src1 = nxt(2048 * 4);
  float* dst1 = nxt(2048 * 4);
  float* sc1  = nxt(2048);
  int*   idx1 = (int*)nxt(1024);
  float* v1   = nxt(1024);
  int*   inv1 = (int*)nxt(2048);
  float* A2m  = nxt(1024 * 1024);
  float* Xpb  = nxt(1024 * 1024);
  float* srcb = nxt(1024 * 2);
  float* dstb = nxt(1024 * 2);
  float* Pu0  = nxt(1024 * 512);
  float* Xpu0 = nxt(2048 * 512);
  float* su0  = nxt(2048 * 4);
  float* du0  = nxt(2048 * 4);
  float* Pu1  = nxt(2048 * 256);
  float* Xpu1 = nxt(4096 * 256);
  float* su1  = nxt(4096 * 4);
  float* du1  = nxt(4096 * 4);
  float* dPp  = nxt(8 * 4096 * 4);                         // denom partials
  float* P    = nxt((size_t)8 * 4096 * 512);               // split-j partials
  float* T1   = nxt((size_t)4096 * 2048);                  // gather-transpose buffer
  unsigned short* XpS  = (unsigned short*)nxt(3200000);    // 3 planes [H][F][N] bf16
  unsigned short* XSp  = (unsigned short*)nxt(1572864);    // 3-plane row split (A side)
  unsigned short* Wd0T = (unsigned short*)nxt(196608);
  unsigned short* Wd1T = (unsigned short*)nxt(786432);
  unsigned short* XpT  = (unsigned short*)nxt(524288);     // [H][F][N] bf16 (single plane)
  unsigned short* X2inB = (unsigned short*)nxt(524288);
  unsigned short* XbB   = (unsigned short*)nxt(524288);
  unsigned short* WbT   = (unsigned short*)nxt(524288);
  unsigned short* Wu0T  = (unsigned short*)nxt(262144);
  unsigned short* Wu1T  = (unsigned short*)nxt(65536);

  // d_ws: final-stage-live buffers (10 MB)
  unsigned short* Xu1B = (unsigned short*)d_ws;                          // 2 MB
  unsigned short* Xu0B = (unsigned short*)((char*)d_ws + (2 << 20));     // 2 MB
  unsigned short* ZB   = (unsigned short*)((char*)d_ws + (4 << 20));     // 4 MB
  unsigned short* Xu1T = (unsigned short*)((char*)d_ws + (8 << 20));     // 2 MB

  // Pz fills the rec1 output region exactly (8 x 8192x256 f32)
  float* Pz = rec1;

  const size_t PS0 = (size_t)512 * 4096;   // XpS plane stride GAT0
  const size_t PS1 = (size_t)1024 * 2048;  // XpS plane stride GAT1

  // ---- A0 = A + I ----
  k_add_eye<<<16384, 256, 0, stream>>>(A, A0);

  // ---- down level 0: GAT(256 -> 4x128), bf16x6 ----
  k_split3<<<1024, 256, 0, stream>>>(X, XSp, (size_t)4096 * 256, 4096 * 256);
  k_transpose_split<<<dim3(8, 4, 1), 256, 0, stream>>>(Wd0, 512, 512, Wd0T, 256,
                                                       (size_t)512 * 256);
  k_gemm_x6_bt<<<dim3(4, 32), 256, 0, stream>>>(XSp, (size_t)4096 * 256, Wd0T,
                                                (size_t)512 * 256, Xp0, XpS, 4096, 512, 256);
  k_src_dst<<<4096, 256, 0, stream>>>(Xp0, asd0, add0, src0, dst0, 4, 128);
  k_gat_x6<<<dim3(4, 32, 4), 512, 0, stream>>>(A0, 4096, XpS, PS0, src0, dst0, P, dPp, 512,
                                               128, 1, 1024);
  k_gat_reduce<<<2048, 256, 0, stream>>>(P, 4, (size_t)4096 * 512, dPp, (size_t)4096 * 4, bd0,
                                         X0, nullptr, 512, 128, 4096 * 512);
  k_score<<<1024, 256, 0, stream>>>(X0, wp0, bp0, sc0, 512);
  k_topk_rank<<<16, 256, 4096 * 8, stream>>>(sc0, 4096, 2048, idx0, v0, inv0);
  k_rowsum_mask<<<2048, 256, 0, stream>>>(A0, 4096, idx0, inv0, sv0);
  k_gatherT<<<dim3(32, 64), 256, 0, stream>>>(A0, 4096, idx0, T1, 2048);
  k_scaleT<<<dim3(2, 2048), 256, 0, stream>>>(T1, 2048, idx0, sv0, A1);

  // ---- down level 1: GAT(512 -> 4x256), bf16x6 ----
  k_gather_scale_split3<<<dim3(1, 2048), 256, 0, stream>>>(X0, 512, idx0, v0, XSp,
                                                           (size_t)2048 * 512);
  k_transpose_split<<<dim3(16, 8, 1), 256, 0, stream>>>(Wd1, 1024, 1024, Wd1T, 512,
                                                        (size_t)1024 * 512);
  k_gemm_x6_bt<<<dim3(8, 16), 256, 0, stream>>>(XSp, (size_t)2048 * 512, Wd1T,
                                                (size_t)1024 * 512, Xp1, XpS, 2048, 1024, 512);
  k_src_dst<<<2048, 256, 0, stream>>>(Xp1, asd1, add1, src1, dst1, 4, 256);
  k_gat_x6<<<dim3(8, 16, 4), 512, 0, stream>>>(A1, 2048, XpS, PS1, src1, dst1, P, dPp, 1024,
                                               256, 2, 512);
  k_gat_reduce<<<2048, 256, 0, stream>>>(P, 4, (size_t)2048 * 1024, dPp, (size_t)2048 * 4, bd1,
                                         X1, nullptr, 1024, 256, 2048 * 1024);
  k_score<<<512, 256, 0, stream>>>(X1, wp1, bp1, sc1, 1024);
  k_topk_rank<<<8, 256, 2048 * 8, stream>>>(sc1, 2048, 1024, idx1, v1, inv1);
  k_gather_mat<<<dim3(4, 1024), 256, 0, stream>>>(A1, 2048, idx1, A2m, 1024);
  k_gather_scale_b16<<<dim3(1, 1024), 256, 0, stream>>>(X1, 1024, idx1, v1, X2inB);

  // ---- bottom: GAT(1024 -> 2x512), bf16 MFMA ----
  k_transpose_bf16<<<dim3(16, 16), 256, 0, stream>>>(Wb, 1024, WbT, 1024, 1024);
  k_gemm_mfma_bt<<<dim3(8, 8), 256, 0, stream>>>(X2inB, WbT, nullptr, Xpb, XpT, 1024, 1024,
                                                 1024);
  k_src_dst<<<1024, 128, 0, stream>>>(Xpb, asb, adb, srcb, dstb, 2, 512);
  k_gat_b16<2, 1><<<dim3(4, 8, 8), 512, 0, stream>>>(A2m, 1024, XpT, srcb, dstb, P, dPp, 1024,
                                                     512, 128);
  k_gat_reduce<<<1024, 256, 0, stream>>>(P, 8, (size_t)1024 * 1024, dPp, (size_t)1024 * 2, bb,
                                         nullptr, XbB, 1024, 512, 1024 * 1024);

  // ---- up level 0: unpool -> GAT(1024 -> 4x128) over A1 ----
  k_transpose_bf16<<<dim3(8, 16), 256, 0, stream>>>(Wu0, 512, Wu0T, 1024, 512);
  k_gemm_mfma_bt<<<dim3(4, 8), 256, 0, stream>>>(XbB, Wu0T, nullptr, Pu0, nullptr, 1024, 512,
                                                 1024);
  k_unpool<<<dim3(2, 2048), 256, 0, stream>>>(Pu0, 512, inv1, Xpu0);
  k_src_dst<<<2048, 256, 0, stream>>>(Xpu0, asu0, adu0, su0, du0, 4, 128);
  k_transpose_bf16h<<<dim3(2, 32, 4), 256, 0, stream>>>(Xpu0, 512, 128, XpT, 2048);
  k_gat_b16<2, 2><<<dim3(2, 16, 8), 512, 0, stream>>>(A1, 2048, XpT, su0, du0, P, dPp, 512,
                                                      128, 256);
  k_gat_reduce<<<1024, 256, 0, stream>>>(P, 8, (size_t)2048 * 512, dPp, (size_t)2048 * 4, bu0,
                                         nullptr, Xu0B, 512, 128, 2048 * 512);

  // ---- up level 1: unpool -> GAT(512 -> 4x64) over A0 ----
  k_transpose_bf16<<<dim3(4, 8), 256, 0, stream>>>(Wu1, 256, Wu1T, 512, 256);
  k_gemm_mfma_bt<<<dim3(2, 16), 256, 0, stream>>>(Xu0B, Wu1T, nullptr, Pu1, nullptr, 2048, 256,
                                                  512);
  k_unpool<<<dim3(1, 4096), 256, 0, stream>>>(Pu1, 256, inv0, Xpu1);
  k_src_dst<<<4096, 256, 0, stream>>>(Xpu1, asu1, adu1, su1, du1, 4, 64);
  k_transpose_bf16h<<<dim3(1, 64, 4), 256, 0, stream>>>(Xpu1, 256, 64, XpT, 4096);
  k_gat_b16<2, 4><<<dim3(1, 32, 8), 512, 0, stream>>>(A0, 4096, XpT, su1, du1, P, dPp, 256,
                                                      64, 512);
  k_gat_reduce<<<1024, 256, 0, stream>>>(P, 8, (size_t)4096 * 256, dPp, (size_t)4096 * 4, bu1,
                                         nullptr, Xu1B, 256, 64, 4096 * 256);
  k_transpose_bb<<<dim3(4, 64), 256, 0, stream>>>(Xu1B, 256, Xu1T, 4096, 256);

  // ---- upsampler: split-k 8 GEMM + fused softmax ----
  k_gemm_aup<<<dim3(8, 64), 512, 0, stream>>>(Wup, Xu1T, Pz, 8192, 4096, 512);
  k_softmax_fuse<<<8192, 256, 0, stream>>>(Pz, 8, (size_t)8192 * 256, bup, ZB);
  k_syrk_mfma<<<dim3(64, 64), 256, 0, stream>>>(ZB, 8192, 256, Aup);

  // ---- reconstructions ----
  k_syrk_mfma<<<dim3(32, 32), 256, 0, stream>>>(Xu1B, 4096, 256, rec1);
  k_syrk_mfma<<<dim3(16, 16), 256, 0, stream>>>(Xu0B, 2048, 512, rec0);
}

// Round 11
// 941.213 us; speedup vs baseline: 1.2148x; 1.2148x over previous
//
#include <hip/hip_runtime.h>
#include <math.h>

// ---------------------------------------------------------------------------
// Graph U-Net forward on MI355X. (Round-9 structure + inv-unpool + aup split-8.)
// Down path = bf16x6 split MFMA (~3e-8 rel err), single-buffered 2-blocks/CU.
// Non-ordering layers = unified multi-head bf16 MFMA GAT (Adj once, exp once,
// denom fused). Coalesced LDS-staged transposes (NOT fused epilogues).
// ---------------------------------------------------------------------------

typedef short bf16x8 __attribute__((ext_vector_type(8)));
typedef float f32x4 __attribute__((ext_vector_type(4)));

static __device__ __forceinline__ float wave_sum64(float v) {
#pragma unroll
  for (int off = 32; off; off >>= 1) v += __shfl_down(v, off);
  return v;
}

static __device__ __forceinline__ unsigned short f2b(float x) {
  unsigned u = __float_as_uint(x);
  unsigned r = (u + 0x7fffu + ((u >> 16) & 1u)) >> 16;
  return (unsigned short)r;
}

static __device__ __forceinline__ float b2f(unsigned short h) {
  return __uint_as_float(((unsigned)h) << 16);
}

// A0 = A + I  (4096x4096), float4
__global__ void k_add_eye(const float* __restrict__ A, float* __restrict__ O) {
  size_t i = ((size_t)blockIdx.x * 256 + threadIdx.x) * 4;
  size_t r = i >> 12, c = i & 4095;
  float4 v = *reinterpret_cast<const float4*>(&A[i]);
  if (r >= c && r < c + 4) ((float*)&v)[r - c] += 1.f;
  *reinterpret_cast<float4*>(&O[i]) = v;
}

// row-major 3-plane bf16 split: D[p*PS + i] = split_p(S[i])
__global__ void k_split3(const float* __restrict__ S, unsigned short* __restrict__ D,
                         size_t PS, int n) {
  int stride = gridDim.x * 1024;
  for (int i = (blockIdx.x * 256 + threadIdx.x) * 4; i < n; i += stride) {
    float4 v = *reinterpret_cast<const float4*>(&S[i]);
    float xv[4] = {v.x, v.y, v.z, v.w};
    unsigned short o1[4], o2[4], o3[4];
#pragma unroll
    for (int e = 0; e < 4; ++e) {
      float x = xv[e];
      unsigned short a = f2b(x);
      float r1 = x - b2f(a);
      unsigned short b = f2b(r1);
      float r2 = r1 - b2f(b);
      o1[e] = a; o2[e] = b; o3[e] = f2b(r2);
    }
    *reinterpret_cast<uint2*>(&D[i]) = *reinterpret_cast<const uint2*>(o1);
    *reinterpret_cast<uint2*>(&D[PS + i]) = *reinterpret_cast<const uint2*>(o2);
    *reinterpret_cast<uint2*>(&D[2 * PS + i]) = *reinterpret_cast<const uint2*>(o3);
  }
}

// gather rows + scale + 3-plane split
__global__ void k_gather_scale_split3(const float* __restrict__ Xs, int Dd,
    const int* __restrict__ idx, const float* __restrict__ v,
    unsigned short* __restrict__ D, size_t PS) {
  int i = blockIdx.y;
  int f = (blockIdx.x * 256 + threadIdx.x) * 4;
  if (f >= Dd) return;
  float vi = v[i];
  float4 x4 = *reinterpret_cast<const float4*>(&Xs[(size_t)idx[i] * Dd + f]);
  float xv[4] = {x4.x * vi, x4.y * vi, x4.z * vi, x4.w * vi};
  unsigned short o1[4], o2[4], o3[4];
#pragma unroll
  for (int e = 0; e < 4; ++e) {
    float x = xv[e];
    unsigned short a = f2b(x);
    float r1 = x - b2f(a);
    unsigned short b = f2b(r1);
    float r2 = r1 - b2f(b);
    o1[e] = a; o2[e] = b; o3[e] = f2b(r2);
  }
  size_t e0 = (size_t)i * Dd + f;
  *reinterpret_cast<uint2*>(&D[e0]) = *reinterpret_cast<const uint2*>(o1);
  *reinterpret_cast<uint2*>(&D[PS + e0]) = *reinterpret_cast<const uint2*>(o2);
  *reinterpret_cast<uint2*>(&D[2 * PS + e0]) = *reinterpret_cast<const uint2*>(o3);
}

// gather rows + scale -> bf16
__global__ void k_gather_scale_b16(const float* __restrict__ Xs, int Dd,
    const int* __restrict__ idx, const float* __restrict__ v,
    unsigned short* __restrict__ D) {
  int i = blockIdx.y;
  int f = (blockIdx.x * 256 + threadIdx.x) * 4;
  if (f >= Dd) return;
  float vi = v[i];
  float4 x4 = *reinterpret_cast<const float4*>(&Xs[(size_t)idx[i] * Dd + f]);
  unsigned short o[4] = {f2b(x4.x * vi), f2b(x4.y * vi), f2b(x4.z * vi), f2b(x4.w * vi)};
  *reinterpret_cast<uint2*>(&D[(size_t)i * Dd + f]) = *reinterpret_cast<const uint2*>(o);
}

// D[c][r] = bf16(S[r*ldS + c]); f32 in
__global__ __launch_bounds__(256) void k_transpose_bf16(const float* __restrict__ S, int ldS,
    unsigned short* __restrict__ D, int R, int Cc) {
  __shared__ unsigned short T[64][72];
  int r0 = blockIdx.y << 6, c0 = blockIdx.x << 6;
  int tid = threadIdx.x;
  int tr = tid >> 4, tc4 = (tid & 15) << 2;
#pragma unroll
  for (int q = 0; q < 4; ++q) {
    int row = tr + q * 16;
    float4 v = *reinterpret_cast<const float4*>(&S[(size_t)(r0 + row) * ldS + c0 + tc4]);
    T[tc4 + 0][row] = f2b(v.x);
    T[tc4 + 1][row] = f2b(v.y);
    T[tc4 + 2][row] = f2b(v.z);
    T[tc4 + 3][row] = f2b(v.w);
  }
  __syncthreads();
#pragma unroll
  for (int q = 0; q < 4; ++q) {
    int row = tr + q * 16;
    *reinterpret_cast<uint2*>(&D[(size_t)(c0 + row) * R + r0 + tc4]) =
        *reinterpret_cast<const uint2*>(&T[row][tc4]);
  }
}

// D[c][r] = S[r*ldS + c]; bf16 in/out
__global__ __launch_bounds__(256) void k_transpose_bb(const unsigned short* __restrict__ S,
    int ldS, unsigned short* __restrict__ D, int R, int Cc) {
  __shared__ unsigned short T[64][72];
  int r0 = blockIdx.y << 6, c0 = blockIdx.x << 6;
  int tid = threadIdx.x;
  int tr = tid >> 4, tc4 = (tid & 15) << 2;
#pragma unroll
  for (int q = 0; q < 4; ++q) {
    int row = tr + q * 16;
    uint2 v = *reinterpret_cast<const uint2*>(&S[(size_t)(r0 + row) * ldS + c0 + tc4]);
    const unsigned short* p = (const unsigned short*)&v;
    T[tc4 + 0][row] = p[0]; T[tc4 + 1][row] = p[1];
    T[tc4 + 2][row] = p[2]; T[tc4 + 3][row] = p[3];
  }
  __syncthreads();
#pragma unroll
  for (int q = 0; q < 4; ++q) {
    int row = tr + q * 16;
    *reinterpret_cast<uint2*>(&D[(size_t)(c0 + row) * R + r0 + tc4]) =
        *reinterpret_cast<const uint2*>(&T[row][tc4]);
  }
}

// per-head transpose: D[(h*F + c)*R + r] = bf16(S[r*ldS + h*F + c])
__global__ __launch_bounds__(256) void k_transpose_bf16h(const float* __restrict__ S, int ldS,
    int F, unsigned short* __restrict__ D, int R) {
  __shared__ unsigned short T[64][72];
  int h = blockIdx.z;
  int r0 = blockIdx.y << 6, c0 = blockIdx.x << 6;
  int tid = threadIdx.x;
  int tr = tid >> 4, tc4 = (tid & 15) << 2;
#pragma unroll
  for (int q = 0; q < 4; ++q) {
    int row = tr + q * 16;
    float4 v = *reinterpret_cast<const float4*>(&S[(size_t)(r0 + row) * ldS + h * F + c0 + tc4]);
    T[tc4 + 0][row] = f2b(v.x);
    T[tc4 + 1][row] = f2b(v.y);
    T[tc4 + 2][row] = f2b(v.z);
    T[tc4 + 3][row] = f2b(v.w);
  }
  __syncthreads();
#pragma unroll
  for (int q = 0; q < 4; ++q) {
    int row = tr + q * 16;
    *reinterpret_cast<uint2*>(&D[((size_t)h * F + c0 + row) * R + r0 + tc4]) =
        *reinterpret_cast<const uint2*>(&T[row][tc4]);
  }
}

// 3-way bf16 split + transpose: D[p*PS + (h*F + c)*R + r] = split_p(S[r][h*F+c])
__global__ __launch_bounds__(256) void k_transpose_split(const float* __restrict__ S, int ldS,
    int F, unsigned short* __restrict__ D, int R, size_t PS) {
  __shared__ unsigned short T[3][64][72];
  int h = blockIdx.z;
  int c0 = blockIdx.x << 6, r0 = blockIdx.y << 6;
  int tid = threadIdx.x;
  int tr = tid >> 4, tc4 = (tid & 15) << 2;
#pragma unroll
  for (int q = 0; q < 4; ++q) {
    int row = tr + q * 16;
    float4 v = *reinterpret_cast<const float4*>(&S[(size_t)(r0 + row) * ldS + h * F + c0 + tc4]);
    float xv[4] = {v.x, v.y, v.z, v.w};
#pragma unroll
    for (int e = 0; e < 4; ++e) {
      float x = xv[e];
      unsigned short h1 = f2b(x);
      float r1 = x - b2f(h1);
      unsigned short h2 = f2b(r1);
      float r2 = r1 - b2f(h2);
      T[0][tc4 + e][row] = h1;
      T[1][tc4 + e][row] = h2;
      T[2][tc4 + e][row] = f2b(r2);
    }
  }
  __syncthreads();
#pragma unroll
  for (int p = 0; p < 3; ++p)
#pragma unroll
    for (int q = 0; q < 4; ++q) {
      int row = tr + q * 16;
      *reinterpret_cast<uint2*>(&D[p * PS + (size_t)(h * F + c0 + row) * R + r0 + tc4]) =
          *reinterpret_cast<const uint2*>(&T[p][row][tc4]);
    }
}

// ---- bf16x6 GEMM: C[M,N] = A @ BT^T from 3-plane splits. 128x128 block. ----
__global__ __launch_bounds__(256, 2) void k_gemm_x6_bt(const unsigned short* __restrict__ As,
    size_t APS, const unsigned short* __restrict__ BTs, size_t BPS, float* __restrict__ C,
    int M, int N, int K) {
  __shared__ __align__(16) unsigned short Ai[3][128 * 40];
  __shared__ __align__(16) unsigned short Bj[3][128 * 40];
  int tid = threadIdx.x;
  int m0 = blockIdx.y << 7, n0 = blockIdx.x << 7;
  int lane = tid & 63, w = tid >> 6;
  int lr = lane & 15, kb = lane >> 4;
  int wr = (w >> 1) << 6, wc = (w & 1) << 6;
  int sr = tid >> 1, sc = (tid & 1) << 4;
  f32x4 acc[4][4] = {};
  for (int k0 = 0; k0 < K; k0 += 32) {
    __syncthreads();
#pragma unroll
    for (int p = 0; p < 3; ++p) {
      const unsigned short* ga = &As[p * APS + (size_t)(m0 + sr) * K + k0 + sc];
      *reinterpret_cast<uint4*>(&Ai[p][sr * 40 + sc]) = *reinterpret_cast<const uint4*>(ga);
      *reinterpret_cast<uint4*>(&Ai[p][sr * 40 + sc + 8]) =
          *reinterpret_cast<const uint4*>(ga + 8);
      const unsigned short* gb = &BTs[p * BPS + (size_t)(n0 + sr) * K + k0 + sc];
      *reinterpret_cast<uint4*>(&Bj[p][sr * 40 + sc]) = *reinterpret_cast<const uint4*>(gb);
      *reinterpret_cast<uint4*>(&Bj[p][sr * 40 + sc + 8]) =
          *reinterpret_cast<const uint4*>(gb + 8);
    }
    __syncthreads();
    bf16x8 af[4][3], bf_[4][3];
#pragma unroll
    for (int m = 0; m < 4; ++m)
#pragma unroll
      for (int p = 0; p < 3; ++p)
        af[m][p] = *reinterpret_cast<const bf16x8*>(&Ai[p][(wr + m * 16 + lr) * 40 + kb * 8]);
#pragma unroll
    for (int n = 0; n < 4; ++n)
#pragma unroll
      for (int p = 0; p < 3; ++p)
        bf_[n][p] = *reinterpret_cast<const bf16x8*>(&Bj[p][(wc + n * 16 + lr) * 40 + kb * 8]);
#pragma unroll
    for (int m = 0; m < 4; ++m)
#pragma unroll
      for (int n = 0; n < 4; ++n) {
        acc[m][n] = __builtin_amdgcn_mfma_f32_16x16x32_bf16(af[m][0], bf_[n][0], acc[m][n], 0, 0, 0);
        acc[m][n] = __builtin_amdgcn_mfma_f32_16x16x32_bf16(af[m][0], bf_[n][1], acc[m][n], 0, 0, 0);
        acc[m][n] = __builtin_amdgcn_mfma_f32_16x16x32_bf16(af[m][1], bf_[n][0], acc[m][n], 0, 0, 0);
        acc[m][n] = __builtin_amdgcn_mfma_f32_16x16x32_bf16(af[m][0], bf_[n][2], acc[m][n], 0, 0, 0);
        acc[m][n] = __builtin_amdgcn_mfma_f32_16x16x32_bf16(af[m][2], bf_[n][0], acc[m][n], 0, 0, 0);
        acc[m][n] = __builtin_amdgcn_mfma_f32_16x16x32_bf16(af[m][1], bf_[n][1], acc[m][n], 0, 0, 0);
      }
  }
  int orow = m0 + wr + (lane >> 4) * 4;
  int ocol = n0 + wc + lr;
#pragma unroll
  for (int m = 0; m < 4; ++m)
#pragma unroll
    for (int n = 0; n < 4; ++n)
#pragma unroll
      for (int r = 0; r < 4; ++r)
        C[(size_t)(orow + m * 16 + r) * N + ocol + n * 16] = acc[m][n][r];
}

// ---- bf16x6 GAT aggregation v4: per-(head,fpart) blocks, single-buffered,
// 62 KB LDS -> 2 blocks/CU. grid: (H*FP, N/128, JC). 512 threads.
__global__ __launch_bounds__(512, 4) void k_gat_x6(const float* __restrict__ Adj, int N,
    const unsigned short* __restrict__ XpS, size_t PS,
    const float* __restrict__ src, const float* __restrict__ dst,
    float* __restrict__ P, float* __restrict__ dP, int HF, int Ffull, int FP, int jchunk) {
  __shared__ __align__(16) unsigned short wL[3][128 * 40];
  __shared__ __align__(16) unsigned short xL[3][128 * 40];
  __shared__ float dstL[128];
  __shared__ float srcL[32];
  int H = HF / Ffull;
  int h = blockIdx.x / FP;
  int fp = blockIdx.x % FP;
  int f0 = fp << 7;
  int i0 = blockIdx.y << 7;
  int jb0 = blockIdx.z * jchunk;
  int tid = threadIdx.x;
  int si = tid >> 2, sj8 = (tid & 3) << 3;
  int lane = tid & 63, w = tid >> 6;
  int lr = lane & 15, kb = lane >> 4;
  int fs = w << 4;
  if (tid < 128) dstL[tid] = dst[(i0 + tid) * H + h];
  float dsum = 0.f;
  f32x4 acc[8] = {};
  int ntiles = jchunk >> 5;
  const unsigned short* xbase = XpS + ((size_t)h * Ffull + f0) * N;
  for (int t = 0; t < ntiles; ++t) {
    int jb = jb0 + (t << 5);
    __syncthreads();  // prev MFMA done
    if (tid < 32) srcL[tid] = src[(jb + tid) * H + h];
    // x stage (no dependence on srcL)
    {
      int frow = tid >> 2;
#pragma unroll
      for (int p = 0; p < 3; ++p)
        *reinterpret_cast<uint4*>(&xL[p][frow * 40 + sj8]) =
            *reinterpret_cast<const uint4*>(&xbase[p * PS + (size_t)frow * N + jb + sj8]);
    }
    float4 av0 = *reinterpret_cast<const float4*>(&Adj[(size_t)(i0 + si) * N + jb + sj8]);
    float4 av1 = *reinterpret_cast<const float4*>(&Adj[(size_t)(i0 + si) * N + jb + sj8 + 4]);
    __syncthreads();  // srcL ready
    {
      int gi = i0 + si;
      float dq = dstL[si];
      const float* a0 = (const float*)&av0;
      const float* a1 = (const float*)&av1;
      unsigned short h1[8], h2[8], h3[8];
      float ds = 0.f;
#pragma unroll
      for (int e = 0; e < 8; ++e) {
        float a = e < 4 ? a0[e] : a1[e - 4];
        float wv = 0.f;
        if (a != 0.f || (jb + sj8 + e) == gi) {
          float tt = dq + srcL[sj8 + e];
          tt = tt >= 0.f ? tt : 0.2f * tt;
          wv = __expf(tt);
        }
        ds += wv;
        unsigned u1 = __float_as_uint(wv);
        h1[e] = (unsigned short)(u1 >> 16);
        float r1 = wv - __uint_as_float(u1 & 0xffff0000u);
        unsigned u2 = __float_as_uint(r1);
        h2[e] = (unsigned short)(u2 >> 16);
        float r2 = r1 - __uint_as_float(u2 & 0xffff0000u);
        h3[e] = (unsigned short)(__float_as_uint(r2) >> 16);
      }
      dsum += ds;
      *reinterpret_cast<uint4*>(&wL[0][si * 40 + sj8]) = *reinterpret_cast<const uint4*>(h1);
      *reinterpret_cast<uint4*>(&wL[1][si * 40 + sj8]) = *reinterpret_cast<const uint4*>(h2);
      *reinterpret_cast<uint4*>(&wL[2][si * 40 + sj8]) = *reinterpret_cast<const uint4*>(h3);
    }
    __syncthreads();  // tile staged
    bf16x8 bf_[3];
#pragma unroll
    for (int p = 0; p < 3; ++p)
      bf_[p] = *reinterpret_cast<const bf16x8*>(&xL[p][(fs + lr) * 40 + kb * 8]);
#pragma unroll
    for (int m = 0; m < 8; ++m) {
      bf16x8 af[3];
#pragma unroll
      for (int p = 0; p < 3; ++p)
        af[p] = *reinterpret_cast<const bf16x8*>(&wL[p][(m * 16 + lr) * 40 + kb * 8]);
      acc[m] = __builtin_amdgcn_mfma_f32_16x16x32_bf16(af[0], bf_[0], acc[m], 0, 0, 0);
      acc[m] = __builtin_amdgcn_mfma_f32_16x16x32_bf16(af[0], bf_[1], acc[m], 0, 0, 0);
      acc[m] = __builtin_amdgcn_mfma_f32_16x16x32_bf16(af[1], bf_[0], acc[m], 0, 0, 0);
      acc[m] = __builtin_amdgcn_mfma_f32_16x16x32_bf16(af[0], bf_[2], acc[m], 0, 0, 0);
      acc[m] = __builtin_amdgcn_mfma_f32_16x16x32_bf16(af[2], bf_[0], acc[m], 0, 0, 0);
      acc[m] = __builtin_amdgcn_mfma_f32_16x16x32_bf16(af[1], bf_[1], acc[m], 0, 0, 0);
    }
  }
  if (fp == 0) {
    float v = dsum;
    v += __shfl_xor(v, 1);
    v += __shfl_xor(v, 2);
    if ((tid & 3) == 0)
      dP[(size_t)blockIdx.z * N * H + (i0 + si) * H + h] = v;
  }
  float* Pc = P + (size_t)blockIdx.z * N * HF;
  int orow = i0 + (lane >> 4) * 4;
  int ocol = h * Ffull + f0 + fs + lr;
#pragma unroll
  for (int m = 0; m < 8; ++m)
#pragma unroll
    for (int r = 0; r < 4; ++r)
      Pc[(size_t)(orow + m * 16 + r) * HF + ocol] = acc[m][r];
}

// ---- unified multi-head bf16 GAT (non-ordering): block covers 128i x (NS*128)hf ----
template <int NS, int HEADS>
__global__ __launch_bounds__(512) void k_gat_b16(const float* __restrict__ Adj, int N,
    const unsigned short* __restrict__ XpT,
    const float* __restrict__ src, const float* __restrict__ dst,
    float* __restrict__ P, float* __restrict__ dP, int HF, int F, int jchunk) {
  constexpr int HFB = NS * 128;
  __shared__ __align__(16) unsigned short wL[HEADS][128 * 40];
  __shared__ __align__(16) unsigned short xL[HFB * 40];
  __shared__ float dstL[HEADS][128];
  __shared__ float srcL[HEADS][32];
  int H = HF / F;
  int hf0 = blockIdx.x * HFB;
  int h0 = hf0 / F;
  int i0 = blockIdx.y << 7;
  int jb0 = blockIdx.z * jchunk;
  int tid = threadIdx.x;
  int si = tid >> 2, sj8 = (tid & 3) << 3;
  int lane = tid & 63, w = tid >> 6;
  int lr = lane & 15, kb = lane >> 4;
  int fs = w * (NS * 16);
  int hw = (hf0 + fs) / F - h0;
  if (tid < HEADS * 128)
    dstL[tid >> 7][tid & 127] = dst[(i0 + (tid & 127)) * H + h0 + (tid >> 7)];
  float dsum[HEADS] = {};
  f32x4 acc[8][NS] = {};
  int ntiles = jchunk >> 5;
  for (int t = 0; t < ntiles; ++t) {
    int jb = jb0 + (t << 5);
    __syncthreads();
    if (tid < HEADS * 32) srcL[tid >> 5][tid & 31] = src[(jb + (tid & 31)) * H + h0 + (tid >> 5)];
    // x stage
#pragma unroll
    for (int base = 0; base < HFB; base += 128) {
      int row = base + (tid >> 2);
      *reinterpret_cast<uint4*>(&xL[row * 40 + sj8]) =
          *reinterpret_cast<const uint4*>(&XpT[(size_t)(hf0 + row) * N + jb + sj8]);
    }
    float4 av0 = *reinterpret_cast<const float4*>(&Adj[(size_t)(i0 + si) * N + jb + sj8]);
    float4 av1 = *reinterpret_cast<const float4*>(&Adj[(size_t)(i0 + si) * N + jb + sj8 + 4]);
    __syncthreads();
    {
      int gi = i0 + si;
      const float* a0 = (const float*)&av0;
      const float* a1 = (const float*)&av1;
#pragma unroll
      for (int hh = 0; hh < HEADS; ++hh) {
        float dq = dstL[hh][si];
        unsigned short wb[8];
        float ds = 0.f;
#pragma unroll
        for (int e = 0; e < 8; ++e) {
          float a = e < 4 ? a0[e] : a1[e - 4];
          float wv = 0.f;
          if (a != 0.f || (jb + sj8 + e) == gi) {
            float tt = dq + srcL[hh][sj8 + e];
            tt = tt >= 0.f ? tt : 0.2f * tt;
            wv = __expf(tt);
          }
          ds += wv;
          wb[e] = f2b(wv);
        }
        dsum[hh] += ds;
        *reinterpret_cast<uint4*>(&wL[hh][si * 40 + sj8]) =
            *reinterpret_cast<const uint4*>(wb);
      }
    }
    __syncthreads();
    bf16x8 bf_[NS];
#pragma unroll
    for (int n = 0; n < NS; ++n)
      bf_[n] = *reinterpret_cast<const bf16x8*>(&xL[(fs + n * 16 + lr) * 40 + kb * 8]);
#pragma unroll
    for (int m = 0; m < 8; ++m) {
      bf16x8 a = *reinterpret_cast<const bf16x8*>(&wL[hw][(m * 16 + lr) * 40 + kb * 8]);
#pragma unroll
      for (int n = 0; n < NS; ++n)
        acc[m][n] = __builtin_amdgcn_mfma_f32_16x16x32_bf16(a, bf_[n], acc[m][n], 0, 0, 0);
    }
  }
#pragma unroll
  for (int hh = 0; hh < HEADS; ++hh) {
    float v = dsum[hh];
    v += __shfl_xor(v, 1);
    v += __shfl_xor(v, 2);
    if ((tid & 3) == 0)
      dP[(size_t)blockIdx.z * N * H + (i0 + si) * H + h0 + hh] = v;
  }
  float* Pc = P + (size_t)blockIdx.z * N * HF;
  int orow = i0 + (lane >> 4) * 4;
  int ocol0 = hf0 + fs + lr;
#pragma unroll
  for (int m = 0; m < 8; ++m)
#pragma unroll
    for (int n = 0; n < NS; ++n)
#pragma unroll
      for (int r = 0; r < 4; ++r)
        Pc[(size_t)(orow + m * 16 + r) * HF + ocol0 + n * 16] = acc[m][n][r];
}

// Out = relu((sum_c P[c]) / (sum_c dP[c]) + bias); optional f32/bf16 outputs
__global__ void k_gat_reduce(const float* __restrict__ P, int nch, size_t chstride,
    const float* __restrict__ dP, size_t dstride, const float* __restrict__ bias,
    float* __restrict__ Of, unsigned short* __restrict__ Ob, int HF, int F, int n_total) {
  int e = (blockIdx.x * 256 + threadIdx.x) * 4;
  if (e >= n_total) return;
  float4 s = *reinterpret_cast<const float4*>(&P[e]);
  for (int c = 1; c < nch; ++c) {
    float4 v = *reinterpret_cast<const float4*>(&P[c * chstride + e]);
    s.x += v.x; s.y += v.y; s.z += v.z; s.w += v.w;
  }
  int i = e / HF;
  int hf = e - i * HF;
  int h = hf / F;
  float den = 0.f;
  for (int c = 0; c < nch; ++c) den += dP[c * dstride + i * (HF / F) + h];
  float inv = 1.f / den;
  float4 bz = *reinterpret_cast<const float4*>(&bias[hf]);
  float4 o;
  o.x = fmaxf(fmaf(s.x, inv, bz.x), 0.f);
  o.y = fmaxf(fmaf(s.y, inv, bz.y), 0.f);
  o.z = fmaxf(fmaf(s.z, inv, bz.z), 0.f);
  o.w = fmaxf(fmaf(s.w, inv, bz.w), 0.f);
  if (Of) *reinterpret_cast<float4*>(&Of[e]) = o;
  if (Ob) {
    unsigned short ob[4] = {f2b(o.x), f2b(o.y), f2b(o.z), f2b(o.w)};
    *reinterpret_cast<uint2*>(&Ob[e]) = *reinterpret_cast<const uint2*>(ob);
  }
}

// ---- bf16 MFMA: C = relu(G @ G^T), 128x128 block, triangular + mirror ----
__global__ __launch_bounds__(256) void k_syrk_mfma(const unsigned short* __restrict__ G,
    int M, int Kd, float* __restrict__ C) {
  if (blockIdx.x < blockIdx.y) return;
  __shared__ __align__(16) unsigned short Ai[128 * 40];
  __shared__ __align__(16) unsigned short Bj[128 * 40];
  int tid = threadIdx.x;
  int i0 = blockIdx.y << 7, j0 = blockIdx.x << 7;
  int srow = tid >> 1, scol = (tid & 1) << 3;
  int lane = tid & 63, w = tid >> 6;
  int wr = (w >> 1) << 6, wc = (w & 1) << 6;
  int lr = lane & 15, kb = lane >> 4;
  f32x4 acc[4][4] = {};
  const unsigned short* gA = G + (size_t)i0 * Kd;
  const unsigned short* gB = G + (size_t)j0 * Kd;
  for (int k0 = 0; k0 < Kd; k0 += 32) {
    __syncthreads();
#pragma unroll
    for (int kk = 0; kk < 32; kk += 16) {
      *reinterpret_cast<uint4*>(&Ai[srow * 40 + scol + kk]) =
          *reinterpret_cast<const uint4*>(&gA[(size_t)srow * Kd + k0 + scol + kk]);
      *reinterpret_cast<uint4*>(&Bj[srow * 40 + scol + kk]) =
          *reinterpret_cast<const uint4*>(&gB[(size_t)srow * Kd + k0 + scol + kk]);
    }
    __syncthreads();
    bf16x8 a[4], b[4];
#pragma unroll
    for (int m = 0; m < 4; ++m)
      a[m] = *reinterpret_cast<const bf16x8*>(&Ai[(wr + m * 16 + lr) * 40 + kb * 8]);
#pragma unroll
    for (int n = 0; n < 4; ++n)
      b[n] = *reinterpret_cast<const bf16x8*>(&Bj[(wc + n * 16 + lr) * 40 + kb * 8]);
#pragma unroll
    for (int m = 0; m < 4; ++m)
#pragma unroll
      for (int n = 0; n < 4; ++n)
        acc[m][n] = __builtin_amdgcn_mfma_f32_16x16x32_bf16(a[m], b[n], acc[m][n], 0, 0, 0);
  }
  int orow = i0 + wr + (lane >> 4) * 4;
  int ocol = j0 + wc + (lane & 15);
  bool mirror = (j0 != i0);
#pragma unroll
  for (int m = 0; m < 4; ++m)
#pragma unroll
    for (int n = 0; n < 4; ++n) {
      float4 v;
      v.x = fmaxf(acc[m][n][0], 0.f);
      v.y = fmaxf(acc[m][n][1], 0.f);
      v.z = fmaxf(acc[m][n][2], 0.f);
      v.w = fmaxf(acc[m][n][3], 0.f);
#pragma unroll
      for (int r = 0; r < 4; ++r)
        C[(size_t)(orow + m * 16 + r) * M + ocol + n * 16] = ((const float*)&v)[r];
      if (mirror)
        *reinterpret_cast<float4*>(
            &C[(size_t)(j0 + wc + n * 16 + lr) * M + i0 + wr + m * 16 + (lane >> 4) * 4]) = v;
    }
}

// C[M,N] = A[M,K] @ BT[N,K]^T (+ bias[m] if non-null). bf16 in, f32 out.
__global__ __launch_bounds__(256) void k_gemm_mfma_bt(const unsigned short* __restrict__ Amat,
    const unsigned short* __restrict__ BT, const float* __restrict__ bias,
    float* __restrict__ C, int M, int N, int Kd) {
  __shared__ __align__(16) unsigned short Ai[128 * 40];
  __shared__ __align__(16) unsigned short Bj[128 * 40];
  int tid = threadIdx.x;
  int m0 = blockIdx.y << 7, n0 = blockIdx.x << 7;
  int srow = tid >> 1, scol = (tid & 1) << 3;
  int lane = tid & 63, w = tid >> 6;
  int wr = (w >> 1) << 6, wc = (w & 1) << 6;
  int lr = lane & 15, kb = lane >> 4;
  f32x4 acc[4][4] = {};
  const unsigned short* gA = Amat + (size_t)m0 * Kd;
  const unsigned short* gB = BT + (size_t)n0 * Kd;
  for (int k0 = 0; k0 < Kd; k0 += 32) {
    __syncthreads();
#pragma unroll
    for (int kk = 0; kk < 32; kk += 16) {
      *reinterpret_cast<uint4*>(&Ai[srow * 40 + scol + kk]) =
          *reinterpret_cast<const uint4*>(&gA[(size_t)srow * Kd + k0 + scol + kk]);
      *reinterpret_cast<uint4*>(&Bj[srow * 40 + scol + kk]) =
          *reinterpret_cast<const uint4*>(&gB[(size_t)srow * Kd + k0 + scol + kk]);
    }
    __syncthreads();
    bf16x8 a[4], b[4];
#pragma unroll
    for (int m = 0; m < 4; ++m)
      a[m] = *reinterpret_cast<const bf16x8*>(&Ai[(wr + m * 16 + lr) * 40 + kb * 8]);
#pragma unroll
    for (int n = 0; n < 4; ++n)
      b[n] = *reinterpret_cast<const bf16x8*>(&Bj[(wc + n * 16 + lr) * 40 + kb * 8]);
#pragma unroll
    for (int m = 0; m < 4; ++m)
#pragma unroll
      for (int n = 0; n < 4; ++n)
        acc[m][n] = __builtin_amdgcn_mfma_f32_16x16x32_bf16(a[m], b[n], acc[m][n], 0, 0, 0);
  }
  int orow = m0 + wr + (lane >> 4) * 4;
  int ocol = n0 + wc + (lane & 15);
#pragma unroll
  for (int m = 0; m < 4; ++m)
#pragma unroll
    for (int n = 0; n < 4; ++n)
#pragma unroll
      for (int r = 0; r < 4; ++r) {
        float rb = bias ? bias[orow + m * 16 + r] : 0.f;
        C[(size_t)(orow + m * 16 + r) * N + ocol + n * 16] = acc[m][n][r] + rb;
      }
}

// ---- upsampler GEMM: Pz[kc] = Wup(f32,staged->bf16) @ Xu1T^T, 128x256 tile, split-k ----
__global__ __launch_bounds__(512) void k_gemm_aup(const float* __restrict__ Wg,
    const unsigned short* __restrict__ BT, float* __restrict__ Pz, int Mtot, int Ktot,
    int kc_len) {
  __shared__ __align__(16) unsigned short Ai[128 * 40];
  __shared__ __align__(16) unsigned short Bj[256 * 40];
  int tid = threadIdx.x;
  int m0 = blockIdx.y << 7;
  int k0base = blockIdx.x * kc_len;
  int lane = tid & 63, w = tid >> 6;
  int wr = (w >> 2) << 6, wc = (w & 3) << 6;
  int lr = lane & 15, kb = lane >> 4;
  int ar = tid >> 2, ac8 = (tid & 3) << 3;
  int br = tid >> 1, bc16 = (tid & 1) << 4;
  f32x4 acc[4][4] = {};
  for (int kk = 0; kk < kc_len; kk += 32) {
    int k0 = k0base + kk;
    __syncthreads();
    {
      const float* arow = &Wg[(size_t)(m0 + ar) * Ktot + k0 + ac8];
      float4 v0 = *reinterpret_cast<const float4*>(arow);
      float4 v1 = *reinterpret_cast<const float4*>(arow + 4);
      unsigned short t8[8] = {f2b(v0.x), f2b(v0.y), f2b(v0.z), f2b(v0.w),
                              f2b(v1.x), f2b(v1.y), f2b(v1.z), f2b(v1.w)};
      *reinterpret_cast<uint4*>(&Ai[ar * 40 + ac8]) = *reinterpret_cast<const uint4*>(t8);
      const unsigned short* brow = &BT[(size_t)br * Ktot + k0 + bc16];
      *reinterpret_cast<uint4*>(&Bj[br * 40 + bc16]) = *reinterpret_cast<const uint4*>(brow);
      *reinterpret_cast<uint4*>(&Bj[br * 40 + bc16 + 8]) =
          *reinterpret_cast<const uint4*>(brow + 8);
    }
    __syncthreads();
    bf16x8 a[4], b[4];
#pragma unroll
    for (int m = 0; m < 4; ++m)
      a[m] = *reinterpret_cast<const bf16x8*>(&Ai[(wr + m * 16 + lr) * 40 + kb * 8]);
#pragma unroll
    for (int n = 0; n < 4; ++n)
      b[n] = *reinterpret_cast<const bf16x8*>(&Bj[(wc + n * 16 + lr) * 40 + kb * 8]);
#pragma unroll
    for (int m = 0; m < 4; ++m)
#pragma unroll
      for (int n = 0; n < 4; ++n)
        acc[m][n] = __builtin_amdgcn_mfma_f32_16x16x32_bf16(a[m], b[n], acc[m][n], 0, 0, 0);
  }
  float* outp = Pz + (size_t)blockIdx.x * Mtot * 256;
  int orow = m0 + wr + (lane >> 4) * 4;
  int ocol = wc + (lane & 15);
#pragma unroll
  for (int m = 0; m < 4; ++m)
#pragma unroll
    for (int n = 0; n < 4; ++n)
#pragma unroll
      for (int r = 0; r < 4; ++r)
        outp[(size_t)(orow + m * 16 + r) * 256 + ocol + n * 16] = acc[m][n][r];
}

// row softmax over 256 cols of (sum_c Pz[c] + bias[row]) -> bf16
__global__ __launch_bounds__(256) void k_softmax_fuse(const float* __restrict__ Pz, int nch,
    size_t chstride, const float* __restrict__ bias, unsigned short* __restrict__ ZB) {
  int row = blockIdx.x, tid = threadIdx.x;
  size_t e = (size_t)row * 256 + tid;
  float x = bias[row];
  for (int c = 0; c < nch; ++c) x += Pz[c * chstride + e];
  float m = x;
#pragma unroll
  for (int off = 32; off; off >>= 1) m = fmaxf(m, __shfl_down(m, off));
  __shared__ float red[4];
  __shared__ float bm, bs;
  if ((tid & 63) == 0) red[tid >> 6] = m;
  __syncthreads();
  if (tid == 0) bm = fmaxf(fmaxf(red[0], red[1]), fmaxf(red[2], red[3]));
  __syncthreads();
  float ev = expf(x - bm);
  float sm = wave_sum64(ev);
  __syncthreads();
  if ((tid & 63) == 0) red[tid >> 6] = sm;
  __syncthreads();
  if (tid == 0) bs = red[0] + red[1] + red[2] + red[3];
  __syncthreads();
  ZB[e] = f2b(ev / bs);
}

// src[n,h] = sum_f Xp[n,h,f]*a_src[h,f]; dst likewise.
__global__ void k_src_dst(const float* __restrict__ Xp, const float* __restrict__ a_src,
    const float* __restrict__ a_dst, float* __restrict__ src, float* __restrict__ dst,
    int H, int F) {
  int n = blockIdx.x;
  int h = threadIdx.x >> 6, lane = threadIdx.x & 63;
  const float* x = Xp + ((size_t)n * H + h) * F;
  const float* as = a_src + h * F;
  const float* ad = a_dst + h * F;
  float ps = 0.f, pd = 0.f;
  for (int f = lane; f < F; f += 64) {
    float xv = x[f];
    ps = fmaf(xv, as[f], ps);
    pd = fmaf(xv, ad[f], pd);
  }
  ps = wave_sum64(ps);
  pd = wave_sum64(pd);
  if (lane == 0) { src[n * H + h] = ps; dst[n * H + h] = pd; }
}

// s[row] = sigmoid(dot(X[row,:], w) + b)
__global__ __launch_bounds__(256) void k_score(const float* __restrict__ Xf,
    const float* __restrict__ wv, const float* __restrict__ bsc, float* __restrict__ s, int D) {
  int row = blockIdx.x * 4 + (threadIdx.x >> 6);
  int lane = threadIdx.x & 63;
  const float* x = Xf + (size_t)row * D;
  float p = 0.f;
  for (int f = lane; f < D; f += 64) p = fmaf(x[f], wv[f], p);
  p = wave_sum64(p);
  if (lane == 0) s[row] = 1.f / (1.f + expf(-(p + bsc[0])));
}

// top-k by exact rank counting; emits idx/vals + inverse rank map (0 = unselected).
__global__ __launch_bounds__(256) void k_topk_rank(const float* __restrict__ s, int n, int k,
    int* __restrict__ idx, float* __restrict__ vals, int* __restrict__ inv) {
  extern __shared__ unsigned long long keys[];
  int tid = threadIdx.x;
  int i = blockIdx.x * 256 + tid;
  for (int j = tid; j < n; j += 256) {
    unsigned u = __float_as_uint(s[j]);
    unsigned ord = (u & 0x80000000u) ? ~u : (u | 0x80000000u);
    keys[j] = ((unsigned long long)ord << 32) | (unsigned)(~j);
  }
  __syncthreads();
  unsigned long long mykey = keys[i];
  int rank = 0;
#pragma unroll 4
  for (int j = 0; j < n; ++j) rank += (keys[j] > mykey);
  int sel = rank < k;
  inv[i] = sel ? rank + 1 : 0;
  if (sel) {
    idx[rank] = i;
    vals[rank] = s[i];
  }
}

// sv[i] = rsqrt(dot(A0[idx[i],:], selected-mask) + 1e-5)
__global__ __launch_bounds__(256) void k_rowsum_mask(const float* __restrict__ A0, int N,
    const int* __restrict__ idx, const int* __restrict__ inv, float* __restrict__ sv) {
  int i = blockIdx.x, tid = threadIdx.x;
  const float* row = A0 + (size_t)idx[i] * N;
  float p = 0.f;
  for (int j = tid * 4; j < N; j += 1024) {
    float4 a = *reinterpret_cast<const float4*>(&row[j]);
    int4 b = *reinterpret_cast<const int4*>(&inv[j]);
    if (b.x) p += a.x;
    if (b.y) p += a.y;
    if (b.z) p += a.z;
    if (b.w) p += a.w;
  }
  p = wave_sum64(p);
  __shared__ float red[4];
  if ((tid & 63) == 0) red[tid >> 6] = p;
  __syncthreads();
  if (tid == 0) sv[i] = rsqrtf(red[0] + red[1] + red[2] + red[3] + 1e-5f);
}

// T1[c][i] = A0[idx[i]][c]
__global__ __launch_bounds__(256) void k_gatherT(const float* __restrict__ A0, int N,
    const int* __restrict__ idx, float* __restrict__ T1, int k) {
  __shared__ float T[64][65];
  int i0 = blockIdx.x << 6, c0 = blockIdx.y << 6;
  int tid = threadIdx.x;
  int tr = tid >> 4, tc4 = (tid & 15) << 2;
#pragma unroll
  for (int q = 0; q < 4; ++q) {
    int row = tr + q * 16;
    float4 v = *reinterpret_cast<const float4*>(&A0[(size_t)idx[i0 + row] * N + c0 + tc4]);
    T[tc4 + 0][row] = v.x; T[tc4 + 1][row] = v.y; T[tc4 + 2][row] = v.z; T[tc4 + 3][row] = v.w;
  }
  __syncthreads();
#pragma unroll
  for (int q = 0; q < 4; ++q) {
    int row = tr + q * 16;
    float4 o;
    o.x = T[row][tc4]; o.y = T[row][tc4 + 1]; o.z = T[row][tc4 + 2]; o.w = T[row][tc4 + 3];
    *reinterpret_cast<float4*>(&T1[(size_t)(c0 + row) * k + i0 + tc4]) = o;
  }
}

// A1[j][i] = T1[idx[j]][i] * sv[j] * sv[i]
__global__ void k_scaleT(const float* __restrict__ T1, int k, const int* __restrict__ idx,
    const float* __restrict__ sv, float* __restrict__ A1) {
  int j = blockIdx.y;
  int i = (blockIdx.x * 256 + threadIdx.x) * 4;
  float sj = sv[j];
  const float* r = T1 + (size_t)idx[j] * k;
  float4 v = *reinterpret_cast<const float4*>(&r[i]);
  float4 s = *reinterpret_cast<const float4*>(&sv[i]);
  v.x *= sj * s.x; v.y *= sj * s.y; v.z *= sj * s.z; v.w *= sj * s.w;
  *reinterpret_cast<float4*>(&A1[(size_t)j * k + i]) = v;
}

__global__ void k_gather_mat(const float* __restrict__ Asrc, int lda,
    const int* __restrict__ idx, float* __restrict__ B, int k) {
  int j = blockIdx.x * 256 + threadIdx.x;
  int i = blockIdx.y;
  B[(size_t)i * k + j] = Asrc[(size_t)idx[i] * lda + idx[j]];
}

// Xo[node] = inv[node] ? P[inv[node]-1] : 0  (single-pass unpool)
__global__ void k_unpool(const float* __restrict__ Pn, int Dd, const int* __restrict__ inv,
                         float* __restrict__ Xo) {
  int node = blockIdx.y;
  int f = blockIdx.x * 256 + threadIdx.x;
  int r = inv[node];
  Xo[(size_t)node * Dd + f] = r ? Pn[(size_t)(r - 1) * Dd + f] : 0.f;
}

extern "C" void kernel_launch(void* const* d_in, const int* in_sizes, int n_in,
                              void* d_out, int out_size, void* d_ws, size_t ws_size,
                              hipStream_t stream) {
  const float* A    = (const float*)d_in[0];
  const float* X    = (const float*)d_in[1];
  const float* Wd0  = (const float*)d_in[2];
  const float* asd0 = (const float*)d_in[3];
  const float* add0 = (const float*)d_in[4];
  const float* bd0  = (const float*)d_in[5];
  const float* Wd1  = (const float*)d_in[6];
  const float* asd1 = (const float*)d_in[7];
  const float* add1 = (const float*)d_in[8];
  const float* bd1  = (const float*)d_in[9];
  const float* wp0  = (const float*)d_in[10];
  const float* bp0  = (const float*)d_in[11];
  const float* wp1  = (const float*)d_in[12];
  const float* bp1  = (const float*)d_in[13];
  const float* Wb   = (const float*)d_in[14];
  const float* asb  = (const float*)d_in[15];
  const float* adb  = (const float*)d_in[16];
  const float* bb   = (const float*)d_in[17];
  const float* Wu0  = (const float*)d_in[18];
  const float* asu0 = (const float*)d_in[19];
  const float* adu0 = (const float*)d_in[20];
  const float* bu0  = (const float*)d_in[21];
  const float* Wu1  = (const float*)d_in[22];
  const float* asu1 = (const float*)d_in[23];
  const float* adu1 = (const float*)d_in[24];
  const float* bu1  = (const float*)d_in[25];
  const float* Wup  = (const float*)d_in[26];
  const float* bup  = (const float*)d_in[27];
  (void)in_sizes; (void)n_in; (void)out_size; (void)ws_size;

  float* out  = (float*)d_out;
  float* Aup  = out;                    // [8192*8192]
  float* A0   = out + 67108864ULL;      // [4096*4096]
  float* A1   = A0 + 16777216ULL;       // [2048*2048]
  float* rec0 = A1 + 4194304ULL;        // [2048*2048]
  float* rec1 = rec0 + 4194304ULL;      // [4096*4096]

  // Scratch in the A_up output region (dead before A_up syrk writes).
  float* S = Aup;
  size_t off = 0;
  auto nxt = [&](size_t n) { float* p = S + off; off += (n + 1023) & ~(size_t)1023; return p; };
  float* Xp0  = nxt(4096 * 512);
  float* X0   = nxt(4096 * 512);
  float* src0 = nxt(4096 * 4);
  float* dst0 = nxt(4096 * 4);
  float* sc0  = nxt(4096);
  int*   idx0 = (int*)nxt(2048);
  float* v0   = nxt(2048);
  float* sv0  = nxt(2048);
  int*   inv0 = (int*)nxt(4096);
  float* Xp1  = nxt(2048 * 1024);
  float* X1   = nxt(2048 * 1024);
  float* src1 = nxt(2048 * 4);
  float* dst1 = nxt(2048 * 4);
  float* sc1  = nxt(2048);
  int*   idx1 = (int*)nxt(1024);
  float* v1   = nxt(1024);
  int*   inv1 = (int*)nxt(2048);
  float* A2m  = nxt(1024 * 1024);
  float* Xpb  = nxt(1024 * 1024);
  float* srcb = nxt(1024 * 2);
  float* dstb = nxt(1024 * 2);
  float* Pu0  = nxt(1024 * 512);
  float* Xpu0 = nxt(2048 * 512);
  float* su0  = nxt(2048 * 4);
  float* du0  = nxt(2048 * 4);
  float* Pu1  = nxt(2048 * 256);
  float* Xpu1 = nxt(4096 * 256);
  float* su1  = nxt(4096 * 4);
  float* du1  = nxt(4096 * 4);
  float* dPp  = nxt(8 * 4096 * 4);                         // denom partials
  float* P    = nxt((size_t)8 * 4096 * 512);               // split-j partials
  float* T1   = nxt((size_t)4096 * 2048);                  // gather-transpose buffer
  unsigned short* XpS  = (unsigned short*)nxt(3200000);    // 3 planes [H][F][N] bf16
  unsigned short* XSp  = (unsigned short*)nxt(1572864);    // 3-plane row split (A side)
  unsigned short* Wd0T = (unsigned short*)nxt(196608);
  unsigned short* Wd1T = (unsigned short*)nxt(786432);
  unsigned short* XpT  = (unsigned short*)nxt(524288);     // [H][F][N] bf16 (single plane)
  unsigned short* X2inB = (unsigned short*)nxt(524288);
  unsigned short* XbB   = (unsigned short*)nxt(524288);
  unsigned short* WbT   = (unsigned short*)nxt(524288);
  unsigned short* Wu0T  = (unsigned short*)nxt(262144);
  unsigned short* Wu1T  = (unsigned short*)nxt(65536);

  // d_ws: final-stage-live buffers (10 MB)
  unsigned short* Xu1B = (unsigned short*)d_ws;                          // 2 MB
  unsigned short* Xu0B = (unsigned short*)((char*)d_ws + (2 << 20));     // 2 MB
  unsigned short* ZB   = (unsigned short*)((char*)d_ws + (4 << 20));     // 4 MB
  unsigned short* Xu1T = (unsigned short*)((char*)d_ws + (8 << 20));     // 2 MB

  // Pz fills the rec1 output region exactly (8 x 8192x256 f32 = 64 MB)
  float* Pz = rec1;

  const size_t PS0 = (size_t)512 * 4096;   // XpS plane stride GAT0 agg
  const size_t PS1 = (size_t)1024 * 2048;  // XpS plane stride GAT1 agg

  // ---- A0 = A + I ----
  k_add_eye<<<16384, 256, 0, stream>>>(A, A0);

  // ---- down level 0: GAT(256 -> 4x128), bf16x6 split MFMA ----
  k_split3<<<1024, 256, 0, stream>>>(X, XSp, (size_t)4096 * 256, 4096 * 256);
  k_transpose_split<<<dim3(8, 4, 1), 256, 0, stream>>>(Wd0, 512, 512, Wd0T, 256,
                                                       (size_t)512 * 256);
  k_gemm_x6_bt<<<dim3(4, 32), 256, 0, stream>>>(XSp, (size_t)4096 * 256, Wd0T,
                                                (size_t)512 * 256, Xp0, 4096, 512, 256);
  k_src_dst<<<4096, 256, 0, stream>>>(Xp0, asd0, add0, src0, dst0, 4, 128);
  k_transpose_split<<<dim3(2, 64, 4), 256, 0, stream>>>(Xp0, 512, 128, XpS, 4096, PS0);
  k_gat_x6<<<dim3(4, 32, 4), 512, 0, stream>>>(A0, 4096, XpS, PS0, src0, dst0, P, dPp, 512,
                                               128, 1, 1024);
  k_gat_reduce<<<2048, 256, 0, stream>>>(P, 4, (size_t)4096 * 512, dPp, (size_t)4096 * 4, bd0,
                                         X0, nullptr, 512, 128, 4096 * 512);
  k_score<<<1024, 256, 0, stream>>>(X0, wp0, bp0, sc0, 512);
  k_topk_rank<<<16, 256, 4096 * 8, stream>>>(sc0, 4096, 2048, idx0, v0, inv0);
  k_rowsum_mask<<<2048, 256, 0, stream>>>(A0, 4096, idx0, inv0, sv0);
  k_gatherT<<<dim3(32, 64), 256, 0, stream>>>(A0, 4096, idx0, T1, 2048);
  k_scaleT<<<dim3(2, 2048), 256, 0, stream>>>(T1, 2048, idx0, sv0, A1);

  // ---- down level 1: GAT(512 -> 4x256), bf16x6 split MFMA ----
  k_gather_scale_split3<<<dim3(1, 2048), 256, 0, stream>>>(X0, 512, idx0, v0, XSp,
                                                           (size_t)2048 * 512);
  k_transpose_split<<<dim3(16, 8, 1), 256, 0, stream>>>(Wd1, 1024, 1024, Wd1T, 512,
                                                        (size_t)1024 * 512);
  k_gemm_x6_bt<<<dim3(8, 16), 256, 0, stream>>>(XSp, (size_t)2048 * 512, Wd1T,
                                                (size_t)1024 * 512, Xp1, 2048, 1024, 512);
  k_src_dst<<<2048, 256, 0, stream>>>(Xp1, asd1, add1, src1, dst1, 4, 256);
  k_transpose_split<<<dim3(4, 32, 4), 256, 0, stream>>>(Xp1, 1024, 256, XpS, 2048, PS1);
  k_gat_x6<<<dim3(8, 16, 4), 512, 0, stream>>>(A1, 2048, XpS, PS1, src1, dst1, P, dPp, 1024,
                                               256, 2, 512);
  k_gat_reduce<<<2048, 256, 0, stream>>>(P, 4, (size_t)2048 * 1024, dPp, (size_t)2048 * 4, bd1,
                                         X1, nullptr, 1024, 256, 2048 * 1024);
  k_score<<<512, 256, 0, stream>>>(X1, wp1, bp1, sc1, 1024);
  k_topk_rank<<<8, 256, 2048 * 8, stream>>>(sc1, 2048, 1024, idx1, v1, inv1);
  k_gather_mat<<<dim3(4, 1024), 256, 0, stream>>>(A1, 2048, idx1, A2m, 1024);
  k_gather_scale_b16<<<dim3(1, 1024), 256, 0, stream>>>(X1, 1024, idx1, v1, X2inB);

  // ---- bottom: GAT(1024 -> 2x512), unified bf16 MFMA ----
  k_transpose_bf16<<<dim3(16, 16), 256, 0, stream>>>(Wb, 1024, WbT, 1024, 1024);
  k_gemm_mfma_bt<<<dim3(8, 8), 256, 0, stream>>>(X2inB, WbT, nullptr, Xpb, 1024, 1024, 1024);
  k_src_dst<<<1024, 128, 0, stream>>>(Xpb, asb, adb, srcb, dstb, 2, 512);
  k_transpose_bf16h<<<dim3(8, 16, 2), 256, 0, stream>>>(Xpb, 1024, 512, XpT, 1024);
  k_gat_b16<4, 1><<<dim3(2, 8, 4), 512, 0, stream>>>(A2m, 1024, XpT, srcb, dstb, P, dPp, 1024,
                                                     512, 256);
  k_gat_reduce<<<1024, 256, 0, stream>>>(P, 4, (size_t)1024 * 1024, dPp, (size_t)1024 * 2, bb,
                                         nullptr, XbB, 1024, 512, 1024 * 1024);

  // ---- up level 0: unpool -> GAT(1024 -> 4x128) over A1, unified bf16 MFMA ----
  k_transpose_bf16<<<dim3(8, 16), 256, 0, stream>>>(Wu0, 512, Wu0T, 1024, 512);
  k_gemm_mfma_bt<<<dim3(4, 8), 256, 0, stream>>>(XbB, Wu0T, nullptr, Pu0, 1024, 512, 1024);
  k_unpool<<<dim3(2, 2048), 256, 0, stream>>>(Pu0, 512, inv1, Xpu0);
  k_src_dst<<<2048, 256, 0, stream>>>(Xpu0, asu0, adu0, su0, du0, 4, 128);
  k_transpose_bf16h<<<dim3(2, 32, 4), 256, 0, stream>>>(Xpu0, 512, 128, XpT, 2048);
  k_gat_b16<4, 4><<<dim3(1, 16, 8), 512, 0, stream>>>(A1, 2048, XpT, su0, du0, P, dPp, 512,
                                                      128, 256);
  k_gat_reduce<<<1024, 256, 0, stream>>>(P, 8, (size_t)2048 * 512, dPp, (size_t)2048 * 4, bu0,
                                         nullptr, Xu0B, 512, 128, 2048 * 512);

  // ---- up level 1: unpool -> GAT(512 -> 4x64) over A0, unified bf16 MFMA ----
  k_transpose_bf16<<<dim3(4, 8), 256, 0, stream>>>(Wu1, 256, Wu1T, 512, 256);
  k_gemm_mfma_bt<<<dim3(2, 16), 256, 0, stream>>>(Xu0B, Wu1T, nullptr, Pu1, 2048, 256, 512);
  k_unpool<<<dim3(1, 4096), 256, 0, stream>>>(Pu1, 256, inv0, Xpu1);
  k_src_dst<<<4096, 256, 0, stream>>>(Xpu1, asu1, adu1, su1, du1, 4, 64);
  k_transpose_bf16h<<<dim3(1, 64, 4), 256, 0, stream>>>(Xpu1, 256, 64, XpT, 4096);
  k_gat_b16<2, 4><<<dim3(1, 32, 8), 512, 0, stream>>>(A0, 4096, XpT, su1, du1, P, dPp, 256,
                                                      64, 512);
  k_gat_reduce<<<1024, 256, 0, stream>>>(P, 8, (size_t)4096 * 256, dPp, (size_t)4096 * 4, bu1,
                                         nullptr, Xu1B, 256, 64, 4096 * 256);
  k_transpose_bb<<<dim3(4, 64), 256, 0, stream>>>(Xu1B, 256, Xu1T, 4096, 256);

  // ---- upsampler: split-k 8 GEMM + fused softmax ----
  k_gemm_aup<<<dim3(8, 64), 512, 0, stream>>>(Wup, Xu1T, Pz, 8192, 4096, 512);
  k_softmax_fuse<<<8192, 256, 0, stream>>>(Pz, 8, (size_t)8192 * 256, bup, ZB);
  k_syrk_mfma<<<dim3(64, 64), 256, 0, stream>>>(ZB, 8192, 256, Aup);

  // ---- reconstructions ----
  k_syrk_mfma<<<dim3(32, 32), 256, 0, stream>>>(Xu1B, 4096, 256, rec1);
  k_syrk_mfma<<<dim3(16, 16), 256, 0, stream>>>(Xu0B, 2048, 512, rec0);
}